// Round 11
// baseline (143.167 us; speedup 1.0000x reference)
//
#include <hip/hip_runtime.h>

#define NN 4096
#define CIN 256
#define O3 384
#define HID 128
#define NHEAD 4
#define DH 32

typedef float f32x4 __attribute__((ext_vector_type(4)));
typedef _Float16 f16x8 __attribute__((ext_vector_type(8)));
typedef _Float16 f16x4 __attribute__((ext_vector_type(4)));
typedef _Float16 f16x2 __attribute__((ext_vector_type(2)));
typedef __fp16 fp16x2_raw __attribute__((ext_vector_type(2)));

__device__ __forceinline__ f16x2 pkrtz(float a, float b) {
  fp16x2_raw r = __builtin_amdgcn_cvt_pkrtz(a, b);
  return __builtin_bit_cast(f16x2, r);
}

// ---------------- prepass: pack W into MFMA A-frag layout (f16), zero scratch ----------------
// Wpk layout: [(m16*K32 + k32)*64 + l] -> f16x8 : row = m16*16 + (l&15), k = k32*32 + (l>>4)*8 + j
__global__ __launch_bounds__(256) void prep(
    const float* __restrict__ Wqkv, const float* __restrict__ Wout,
    _Float16* __restrict__ WpkA, _Float16* __restrict__ WpkB,
    float* __restrict__ zbase, int nz) {
  const int bid = blockIdx.x, tid = threadIdx.x;
  if (bid < 48) {                       // Wqkv: 24 m16 * 8 k32 * 64 = 12288 threads
    int t = bid * 256 + tid;
    int l = t & 63, mk = t >> 6;
    int k32 = mk & 7, m16 = mk >> 3;
    int row = m16 * 16 + (l & 15), k = k32 * 32 + (l >> 4) * 8;
    const float* s = Wqkv + (size_t)row * CIN + k;
    f16x8 o;
#pragma unroll
    for (int j = 0; j < 8; j++) o[j] = (_Float16)s[j];
    *(f16x8*)(WpkA + (size_t)t * 8) = o;
  } else if (bid < 64) {                // Wout: 16 m16 * 4 k32 * 64 = 4096 threads
    int t = (bid - 48) * 256 + tid;
    int l = t & 63, mk = t >> 6;
    int k32 = mk & 3, m16 = mk >> 2;
    int row = m16 * 16 + (l & 15), k = k32 * 32 + (l >> 4) * 8;
    const float* s = Wout + (size_t)row * HID + k;
    f16x8 o;
#pragma unroll
    for (int j = 0; j < 8; j++) o[j] = (_Float16)s[j];
    *(f16x8*)(WpkB + (size_t)t * 8) = o;
  } else {
    int i = (bid - 64) * 256 + tid;
    if (i < nz) zbase[i] = 0.f;
  }
}

// ---------------- GEMM1 + attn1 fused, v12 ----------------
// v12 = v11 with the exp-redundancy fixed (attn1's exp-once structure restored):
// K-staging waves write exp(f32(f16(acc))) as f32 into Ke[64][68]; V stages f16 into
// Vp[64][68]. Inner loop is pure FMA on broadcast LDS reads -- no transcendentals on the
// post-barrier critical path (v11 recomputed each exp 8x per lane-group at 1/4 rate,
// ~4K cyc/wave of trans serialization -> the 86us regression).
__global__ __launch_bounds__(256) void gemm_qkv(
    const float* __restrict__ X, const _Float16* __restrict__ Wpk,
    _Float16* __restrict__ Yt, float* __restrict__ ctx_raw,
    float* __restrict__ srow_raw) {
  __shared__ __align__(16) _Float16 Bs[2][6656];  // 26624 B: k-loop dbuf 2x5120; epilogue Ke+Vp
  const int orig = blockIdx.x;          // 1536 blocks, 1536 % 8 == 0
  const int swz = (orig & 7) * 192 + (orig >> 3);
  const int mt = swz % 3;
  const int nb = swz / 3;
  const int n0 = (nb & 31) << 7;
  const int b  = nb >> 5;
  const float* Xb = X + (size_t)b * CIN * NN;
  _Float16* Yb = Yt + (size_t)b * NN * O3;
  const int tid = threadIdx.x, l = tid & 63, wid = tid >> 6;
  const int wm = (wid >> 1) << 6, wn = (wid & 1) << 6;
  const int fr = l & 15, q = l >> 4;
  const int b_n = (tid & 31) << 2, b_kk = (tid >> 5) << 2;
  // m16-frag base: Q -> 0..7; KV: K pair at 8+(mt-1)*4, V pair at +8
  const int am16 = (mt == 0) ? (wm >> 4) : (8 + (mt - 1) * 4 + (wm ? 8 : 0));
  // write-side swizzle: rows r = b_n+j share r>>2 = tid&31 (j<4)
  const int tp = tid & 31;
  const int swz3 = ((tp ^ (tp >> 2)) & 3) << 1;           // even, 3-bit
  const int gw4 = (((tid >> 5) ^ swz3) << 2);             // f16 offset of swizzled 8B granule
  // read-side swizzle: per-fn offsets, loop-invariant
  int roff[4];
#pragma unroll
  for (int fn = 0; fn < 4; fn++) {
    const int R = wn + fn * 16 + fr;
    const int sR = ((R >> 2) ^ (R >> 4)) & 3;
    roff[fn] = R * 40 + ((q ^ sR) << 3);                  // f16 units, 16B aligned
  }

#define LOADX(dst, t_) do { \
    _Pragma("unroll") \
    for (int r_ = 0; r_ < 4; r_++) \
      dst[r_] = *(const f32x4*)(Xb + (size_t)((t_) * 32 + b_kk + r_) * NN + n0 + b_n); \
  } while (0)
#define LOADAH(dst, t_) do { \
    _Pragma("unroll") \
    for (int fm_ = 0; fm_ < 4; fm_++) \
      dst[fm_] = *(const f16x8*)(Wpk + ((size_t)((am16 + fm_) * 8 + (t_)) * 64 + l) * 8); \
  } while (0)
#define CVTW(buf_, src) do { \
    _Pragma("unroll") \
    for (int j_ = 0; j_ < 4; j_++) { \
      f16x2 p0_ = pkrtz(src[0][j_], src[1][j_]); \
      f16x2 p1_ = pkrtz(src[2][j_], src[3][j_]); \
      *(f16x4*)&Bs[buf_][(b_n + j_) * 40 + gw4] = (f16x4){p0_[0], p0_[1], p1_[0], p1_[1]}; \
    } } while (0)

  f32x4 xr[3][4];                     // 3-deep rotation: X chunk in flight 2 k-steps
  f16x8 ah[2][4];
  f32x4 acc[4][4];
#pragma unroll
  for (int i = 0; i < 4; i++)
#pragma unroll
    for (int j = 0; j < 4; j++) acc[i][j] = (f32x4){0.f, 0.f, 0.f, 0.f};

  // prologue: chunk0 -> Bs[0]; issue ah(0), chunk1, chunk2 (stay in flight across barrier)
  LOADX(xr[0], 0);
  CVTW(0, xr[0]);
  LOADAH(ah[0], 0);
  LOADX(xr[1], 1);
  LOADX(xr[2], 2);
  asm volatile("s_waitcnt lgkmcnt(0)" ::: "memory");
  __builtin_amdgcn_s_barrier();
  __builtin_amdgcn_sched_barrier(0);

#pragma unroll
  for (int t = 0; t < 8; t++) {
    const int cur = t & 1, nxt = cur ^ 1;
    f16x8 bh[4];
#pragma unroll
    for (int fn = 0; fn < 4; fn++)
      bh[fn] = *(const f16x8*)&Bs[cur][roff[fn]];
#pragma unroll
    for (int fm = 0; fm < 4; fm++)
#pragma unroll
      for (int fn = 0; fn < 4; fn++)
        acc[fm][fn] = __builtin_amdgcn_mfma_f32_16x16x32_f16(ah[cur][fm], bh[fn], acc[fm][fn], 0, 0, 0);
    if (t < 7) {
      CVTW(nxt, xr[(t + 1) % 3]);   // chunk t+1, issued 2+ k-steps ago
      LOADAH(ah[nxt], t + 1);       // issue next Wpk frags (L2, 1-step flight)
      if (t < 5) LOADX(xr[(t + 3) % 3], t + 3);  // FIFO: ah-wait forces only this iter's X
    }
    asm volatile("s_waitcnt lgkmcnt(0)" ::: "memory");
    __builtin_amdgcn_s_barrier();
    __builtin_amdgcn_sched_barrier(0);
  }

  if (mt == 0) {
    // ---- Q: LDS-transpose epilogue (v9, proven): coalesced f16x8 stores of ch 0..127 ----
    _Float16* Ep = &Bs[0][0];           // [64][132] f16, 16896 B
    const int st_n = tid >> 4;          // 0..15
    const int st_m8 = (tid & 15) * 8;   // 0..120
#pragma unroll
    for (int p = 0; p < 2; p++) {
      if ((wid & 1) == p) {             // waves with wn == p*64 hold rows n_local = fn*16+fr
#pragma unroll
        for (int fm = 0; fm < 4; fm++) {
          const int ml = wm + fm * 16 + q * 4;
#pragma unroll
          for (int fn = 0; fn < 4; fn++) {
            const int nl = fn * 16 + fr;
            f16x2 h0 = pkrtz(acc[fm][fn][0], acc[fm][fn][1]);
            f16x2 h1 = pkrtz(acc[fm][fn][2], acc[fm][fn][3]);
            *(f16x4*)&Ep[nl * 132 + ml] = (f16x4){h0[0], h0[1], h1[0], h1[1]};
          }
        }
      }
      __syncthreads();
#pragma unroll
      for (int s = 0; s < 4; s++) {
        const int nl = s * 16 + st_n;
        f16x4 lo = *(const f16x4*)&Ep[nl * 132 + st_m8];
        f16x4 hi = *(const f16x4*)&Ep[nl * 132 + st_m8 + 4];
        f16x8 v = (f16x8){lo[0], lo[1], lo[2], lo[3], hi[0], hi[1], hi[2], hi[3]};
        *(f16x8*)(Yb + (size_t)(n0 + p * 64 + nl) * O3 + st_m8) = v;
      }
      if (p == 0) __syncthreads();      // protect buffer reuse for pass 1
    }
  } else {
    // ---- KV fused attn1, exp-once. Ke f32 [64 nl][68] (K exp'd at stage), Vp f16 [64][68].
    float* Ke = (float*)&Bs[0][0];                          // 17408 B
    _Float16* Vp = (_Float16*)((char*)&Bs[0][0] + 17408);   // 8704 B
    const int hl = wid >> 1;            // head-local 0/1
    const int nbase = (wid & 1) << 5;   // 0/32 within the 64-n pass
    const int d4 = (l >> 3) << 2, e4 = (l & 7) << 2;
    float cacc[4][4];
    float sacc2[4] = {0.f, 0.f, 0.f, 0.f};
#pragma unroll
    for (int i = 0; i < 4; i++)
#pragma unroll
      for (int j = 0; j < 4; j++) cacc[i][j] = 0.f;

#pragma unroll
    for (int p = 0; p < 2; p++) {
      if ((wid & 1) == p) {             // stage this n-half (f16 rounding identical to v9/v11)
        if (wid < 2) {                  // wm==0: K rows 0..63 -> exp'd f32
#pragma unroll
          for (int fm = 0; fm < 4; fm++) {
            const int ml = fm * 16 + q * 4;
#pragma unroll
            for (int fn = 0; fn < 4; fn++) {
              const int nl = fn * 16 + fr;
              f16x2 h0 = pkrtz(acc[fm][fn][0], acc[fm][fn][1]);
              f16x2 h1 = pkrtz(acc[fm][fn][2], acc[fm][fn][3]);
              float4 e;
              e.x = __expf((float)h0[0]); e.y = __expf((float)h0[1]);
              e.z = __expf((float)h1[0]); e.w = __expf((float)h1[1]);
              *(float4*)&Ke[nl * 68 + ml] = e;
            }
          }
        } else {                        // wm==64: V rows -> f16, col = ml-64
#pragma unroll
          for (int fm = 0; fm < 4; fm++) {
            const int mv = fm * 16 + q * 4;
#pragma unroll
            for (int fn = 0; fn < 4; fn++) {
              const int nl = fn * 16 + fr;
              f16x2 h0 = pkrtz(acc[fm][fn][0], acc[fm][fn][1]);
              f16x2 h1 = pkrtz(acc[fm][fn][2], acc[fm][fn][3]);
              *(f16x4*)&Vp[nl * 68 + mv] = (f16x4){h0[0], h0[1], h1[0], h1[1]};
            }
          }
        }
      }
      __syncthreads();
      for (int it = 0; it < 32; ++it) {
        const int nl = nbase + it;
        float ke4[4];
        *(float4*)ke4 = *(const float4*)&Ke[nl * 68 + hl * 32 + d4];
        f16x4 vx = *(const f16x4*)&Vp[nl * 68 + hl * 32 + e4];
        float vf[4];
#pragma unroll
        for (int j = 0; j < 4; j++) vf[j] = (float)vx[j];
#pragma unroll
        for (int i = 0; i < 4; i++) {
          sacc2[i] += ke4[i];
#pragma unroll
          for (int j = 0; j < 4; j++) cacc[i][j] = fmaf(ke4[i], vf[j], cacc[i][j]);
        }
      }
      __syncthreads();
    }
    // reduce: LDS-first (attn1 pattern), then global atomics
    float* red = (float*)&Bs[0][0];     // [2][32][33] ctx + [2][32] srow = 2176 f32, 8704 B
    for (int i = tid; i < 2 * 32 * 33 + 2 * 32; i += 256) red[i] = 0.f;
    __syncthreads();
    float* ch = red + hl * (32 * 33);
#pragma unroll
    for (int i = 0; i < 4; i++)
#pragma unroll
      for (int j = 0; j < 4; j++) atomicAdd(&ch[(d4 + i) * 33 + e4 + j], cacc[i][j]);
    if (e4 == 0) {
#pragma unroll
      for (int i = 0; i < 4; i++) atomicAdd(&red[2112 + hl * 32 + d4 + i], sacc2[i]);
    }
    __syncthreads();
    const int hb = (mt - 1) * 2;
    float* cg = ctx_raw + ((size_t)b * NHEAD + hb) * (DH * DH);
    float* sg = srow_raw + ((size_t)b * NHEAD + hb) * DH;
    for (int i = tid; i < 2 * DH * DH; i += 256) {
      const int h_l = i >> 10, idx = i & 1023;
      atomicAdd(&cg[h_l * DH * DH + idx], red[h_l * 1056 + (idx >> 5) * 33 + (idx & 31)]);
    }
    if (tid < 2 * DH) atomicAdd(&sg[tid], red[2112 + tid]);
  }
#undef LOADX
#undef LOADAH
#undef CVTW
}

// ---------------- attn2: thread-per-column q-softmax + out = ctx^T q, in-place f16 ----------------
// grid (16, NHEAD, 16), block 256
__global__ __launch_bounds__(256) void attn2(
    _Float16* __restrict__ qkvt, const float* __restrict__ ctx_raw,
    const float* __restrict__ srow_raw) {
  const int ns = blockIdx.x, h = blockIdx.y, b = blockIdx.z;
  const float* cg = ctx_raw + (size_t)(b * NHEAD + h) * (DH * DH);
  const float* sr = srow_raw + (size_t)(b * NHEAD + h) * DH;
  __shared__ float ctxs[DH][DH + 1];
  const int tid = threadIdx.x;
  for (int i = tid; i < DH * DH; i += 256) ctxs[i >> 5][i & 31] = cg[i] / sr[i >> 5];
  __syncthreads();
  const int n = ns * 256 + tid;
  _Float16* qp = qkvt + ((size_t)b * NN + n) * O3 + h * DH;
  float qv[DH];
#pragma unroll
  for (int i = 0; i < 4; i++) {
    f16x8 v = *(const f16x8*)(qp + i * 8);
#pragma unroll
    for (int j = 0; j < 8; j++) qv[i * 8 + j] = (float)v[j];
  }
  float m = -1e30f;
#pragma unroll
  for (int d = 0; d < DH; d++) m = fmaxf(m, qv[d]);
  float s = 0.f;
#pragma unroll
  for (int d = 0; d < DH; d++) { qv[d] = __expf(qv[d] - m); s += qv[d]; }
  float inv = 0.17677669529663687f / s;  // scale = 32^-0.5
#pragma unroll
  for (int d = 0; d < DH; d++) qv[d] *= inv;
#pragma unroll
  for (int eo = 0; eo < 4; eo++) {
    float o[8];
#pragma unroll
    for (int j = 0; j < 8; j++) o[j] = 0.f;
#pragma unroll
    for (int d = 0; d < DH; d++) {
      float qd = qv[d];
#pragma unroll
      for (int j = 0; j < 8; j++) o[j] = fmaf(ctxs[d][eo * 8 + j], qd, o[j]);
    }
    f16x2 h0 = pkrtz(o[0], o[1]);
    f16x2 h1 = pkrtz(o[2], o[3]);
    f16x2 h2 = pkrtz(o[4], o[5]);
    f16x2 h3 = pkrtz(o[6], o[7]);
    f16x8 ov = (f16x8){h0[0], h0[1], h1[0], h1[1], h2[0], h2[1], h3[0], h3[1]};
    *(f16x8*)(qp + eo * 8) = ov;
  }
}

// ---------------- proj pass 1: GEMM (no store) -> GN stats only ----------------
// grid (2, 32, 16), block 256.
__global__ __launch_bounds__(256) void proj_stats(
    const _Float16* __restrict__ At, const _Float16* __restrict__ Wpk,
    const float* __restrict__ bias, double* __restrict__ stats) {
  __shared__ _Float16 Bs[128][40];
  const int mt = blockIdx.x;
  const int n0 = blockIdx.y * 128;
  const int b = blockIdx.z;
  const _Float16* Ab = At + (size_t)b * NN * O3;
  const int tid = threadIdx.x, l = tid & 63, wid = tid >> 6;
  const int wm = (wid >> 1) << 6, wn = (wid & 1) << 6;
  const int fr = l & 15, q = l >> 4, kq = q << 3;
  const int am16 = mt * 8 + (wm >> 4);
  const int sr0 = tid >> 2, sc = (tid & 3) << 3;   // rows 0..63, cols {0,8,16,24}

  f32x4 acc[4][4];
#pragma unroll
  for (int i = 0; i < 4; i++)
#pragma unroll
    for (int j = 0; j < 4; j++) acc[i][j] = (f32x4){0.f, 0.f, 0.f, 0.f};

  for (int k0 = 0; k0 < HID; k0 += 32) {
    f16x8 v0 = *(const f16x8*)(Ab + (size_t)(n0 + sr0) * O3 + k0 + sc);
    f16x8 v1 = *(const f16x8*)(Ab + (size_t)(n0 + 64 + sr0) * O3 + k0 + sc);
    f16x8 ah[4];
#pragma unroll
    for (int fm = 0; fm < 4; fm++)
      ah[fm] = *(const f16x8*)(Wpk + ((size_t)((am16 + fm) * 4 + (k0 >> 5)) * 64 + l) * 8);
    __syncthreads();
    *(f16x8*)&Bs[sr0][sc] = v0;
    *(f16x8*)&Bs[64 + sr0][sc] = v1;
    __syncthreads();
    f16x8 bh[4];
#pragma unroll
    for (int fn = 0; fn < 4; fn++)
      bh[fn] = *(const f16x8*)&Bs[wn + fn * 16 + fr][kq];
#pragma unroll
    for (int fm = 0; fm < 4; fm++)
#pragma unroll
      for (int fn = 0; fn < 4; fn++)
        acc[fm][fn] = __builtin_amdgcn_mfma_f32_16x16x32_f16(ah[fm], bh[fn], acc[fm][fn], 0, 0, 0);
  }
  float lsum = 0.f, lsq = 0.f;
#pragma unroll
  for (int fm = 0; fm < 4; fm++) {
    int rowb = mt * 128 + wm + fm * 16 + q * 4;
#pragma unroll
    for (int r = 0; r < 4; r++) {
      float bv = bias[rowb + r];
#pragma unroll
      for (int fn = 0; fn < 4; fn++) {
        float v = acc[fm][fn][r] + bv;
        lsum += v;
        lsq += v * v;
      }
    }
  }
  double ds = (double)lsum, dq = (double)lsq;
#pragma unroll
  for (int off = 32; off; off >>= 1) {
    ds += __shfl_down(ds, off);
    dq += __shfl_down(dq, off);
  }
  __shared__ double sred[8];
  if (l == 0) { sred[wid] = ds; sred[4 + wid] = dq; }
  __syncthreads();
  if (tid == 0) {
    atomicAdd(&stats[b * 2 + 0], sred[0] + sred[1] + sred[2] + sred[3]);
    atomicAdd(&stats[b * 2 + 1], sred[4] + sred[5] + sred[6] + sred[7]);
  }
}

// ---------------- proj pass 2: recompute GEMM, write normalized out ----------------
// grid (2, 32, 16), block 256.
__global__ __launch_bounds__(256) void proj_write(
    const _Float16* __restrict__ At, const _Float16* __restrict__ Wpk,
    const float* __restrict__ bias, float* __restrict__ out,
    const double* __restrict__ stats, const float* __restrict__ gamma,
    const float* __restrict__ beta) {
  __shared__ _Float16 Bs[128][40];
  const int mt = blockIdx.x;
  const int n0 = blockIdx.y * 128;
  const int b = blockIdx.z;
  const _Float16* Ab = At + (size_t)b * NN * O3;
  float* outb = out + (size_t)b * CIN * NN;
  const int tid = threadIdx.x, l = tid & 63, wid = tid >> 6;
  const int wm = (wid >> 1) << 6, wn = (wid & 1) << 6;
  const int fr = l & 15, q = l >> 4, kq = q << 3;
  const int am16 = mt * 8 + (wm >> 4);
  const int sr0 = tid >> 2, sc = (tid & 3) << 3;   // rows 0..63, cols {0,8,16,24}

  const double nels = (double)CIN * (double)NN;
  double S = stats[b * 2 + 0], Q2 = stats[b * 2 + 1];
  double mu = S / nels;
  double var = Q2 / nels - mu * mu;
  const float mean = (float)mu;
  const float rstd = (float)rsqrt(var + 1e-5);

  f32x4 acc[4][4];
#pragma unroll
  for (int i = 0; i < 4; i++)
#pragma unroll
    for (int j = 0; j < 4; j++) acc[i][j] = (f32x4){0.f, 0.f, 0.f, 0.f};

  for (int k0 = 0; k0 < HID; k0 += 32) {
    f16x8 v0 = *(const f16x8*)(Ab + (size_t)(n0 + sr0) * O3 + k0 + sc);
    f16x8 v1 = *(const f16x8*)(Ab + (size_t)(n0 + 64 + sr0) * O3 + k0 + sc);
    f16x8 ah[4];
#pragma unroll
    for (int fm = 0; fm < 4; fm++)
      ah[fm] = *(const f16x8*)(Wpk + ((size_t)((am16 + fm) * 4 + (k0 >> 5)) * 64 + l) * 8);
    __syncthreads();
    *(f16x8*)&Bs[sr0][sc] = v0;
    *(f16x8*)&Bs[64 + sr0][sc] = v1;
    __syncthreads();
    f16x8 bh[4];
#pragma unroll
    for (int fn = 0; fn < 4; fn++)
      bh[fn] = *(const f16x8*)&Bs[wn + fn * 16 + fr][kq];
#pragma unroll
    for (int fm = 0; fm < 4; fm++)
#pragma unroll
      for (int fn = 0; fn < 4; fn++)
        acc[fm][fn] = __builtin_amdgcn_mfma_f32_16x16x32_f16(ah[fm], bh[fn], acc[fm][fn], 0, 0, 0);
  }
#pragma unroll
  for (int fm = 0; fm < 4; fm++) {
    int rowb = mt * 128 + wm + fm * 16 + q * 4;
#pragma unroll
    for (int r = 0; r < 4; r++) {
      int row = rowb + r;
      float bv = bias[row];
      float g = gamma[row] * rstd, bt = beta[row];
      float* dst = outb + (size_t)row * NN + n0 + wn + fr;
#pragma unroll
      for (int fn = 0; fn < 4; fn++) {
        float v = acc[fm][fn][r] + bv;
        dst[fn * 16] = (v - mean) * g + bt;
      }
    }
  }
}

extern "C" void kernel_launch(void* const* d_in, const int* in_sizes, int n_in,
                              void* d_out, int out_size, void* d_ws, size_t ws_size,
                              hipStream_t stream) {
  const float* x     = (const float*)d_in[0];
  const float* Wqkv  = (const float*)d_in[1];
  const float* Wout  = (const float*)d_in[2];
  const float* bout  = (const float*)d_in[3];
  const float* gamma = (const float*)d_in[4];
  const float* beta  = (const float*)d_in[5];
  float* out = (float*)d_out;

  char* ws = (char*)d_ws;
  _Float16* qkvt = (_Float16*)ws;                             // [16][4096][384] f16 (ch 0..127 used)
  size_t off = (size_t)16 * NN * O3 * 2;                      // 50331648 B
  _Float16* WpkA = (_Float16*)(ws + off); off += 48 * 256 * 8 * 2;   // 196608 B
  _Float16* WpkB = (_Float16*)(ws + off); off += 16 * 256 * 8 * 2;   // 65536 B
  float* ctxg = (float*)(ws + off); off += (size_t)16 * NHEAD * DH * DH * 4;
  float* srow = (float*)(ws + off); off += (size_t)16 * NHEAD * DH * 4;
  double* stats = (double*)(ws + off);

  const int nz = 16 * NHEAD * DH * DH + 16 * NHEAD * DH + 64;
  prep<<<64 + (nz + 255) / 256, 256, 0, stream>>>(Wqkv, Wout, WpkA, WpkB, ctxg, nz);
  gemm_qkv<<<dim3(1536), 256, 0, stream>>>(x, WpkA, qkvt, ctxg, srow);
  attn2<<<dim3(16, NHEAD, 16), 256, 0, stream>>>(qkvt, ctxg, srow);
  proj_stats<<<dim3(2, 32, 16), 256, 0, stream>>>(qkvt, WpkB, bout, stats);
  proj_write<<<dim3(2, 32, 16), 256, 0, stream>>>(qkvt, WpkB, bout, out, stats, gamma, beta);
}

// Round 12
// 128.295 us; speedup vs baseline: 1.1159x; 1.1159x over previous
//
#include <hip/hip_runtime.h>

#define NN 4096
#define CIN 256
#define O3 384
#define HID 128
#define NHEAD 4
#define DH 32

typedef float f32x4 __attribute__((ext_vector_type(4)));
typedef _Float16 f16x8 __attribute__((ext_vector_type(8)));
typedef _Float16 f16x4 __attribute__((ext_vector_type(4)));
typedef _Float16 f16x2 __attribute__((ext_vector_type(2)));
typedef __fp16 fp16x2_raw __attribute__((ext_vector_type(2)));

__device__ __forceinline__ f16x2 pkrtz(float a, float b) {
  fp16x2_raw r = __builtin_amdgcn_cvt_pkrtz(a, b);
  return __builtin_bit_cast(f16x2, r);
}

// ---------------- prepass: pack W into MFMA A-frag layout (f16), zero scratch ----------------
// Wpk layout: [(m16*K32 + k32)*64 + l] -> f16x8 : row = m16*16 + (l&15), k = k32*32 + (l>>4)*8 + j
__global__ __launch_bounds__(256) void prep(
    const float* __restrict__ Wqkv, const float* __restrict__ Wout,
    _Float16* __restrict__ WpkA, _Float16* __restrict__ WpkB,
    float* __restrict__ zbase, int nz) {
  const int bid = blockIdx.x, tid = threadIdx.x;
  if (bid < 48) {                       // Wqkv: 24 m16 * 8 k32 * 64 = 12288 threads
    int t = bid * 256 + tid;
    int l = t & 63, mk = t >> 6;
    int k32 = mk & 7, m16 = mk >> 3;
    int row = m16 * 16 + (l & 15), k = k32 * 32 + (l >> 4) * 8;
    const float* s = Wqkv + (size_t)row * CIN + k;
    f16x8 o;
#pragma unroll
    for (int j = 0; j < 8; j++) o[j] = (_Float16)s[j];
    *(f16x8*)(WpkA + (size_t)t * 8) = o;
  } else if (bid < 64) {                // Wout: 16 m16 * 4 k32 * 64 = 4096 threads
    int t = (bid - 48) * 256 + tid;
    int l = t & 63, mk = t >> 6;
    int k32 = mk & 3, m16 = mk >> 2;
    int row = m16 * 16 + (l & 15), k = k32 * 32 + (l >> 4) * 8;
    const float* s = Wout + (size_t)row * HID + k;
    f16x8 o;
#pragma unroll
    for (int j = 0; j < 8; j++) o[j] = (_Float16)s[j];
    *(f16x8*)(WpkB + (size_t)t * 8) = o;
  } else {
    int i = (bid - 64) * 256 + tid;
    if (i < nz) zbase[i] = 0.f;
  }
}

// ---------------- GEMM1: qkvt[b][n][o] = (Wqkv @ X[b])^T, f16 out ----------------
// v10 (reverted, proven 44-47us): v6 k-loop + 3-deep X prefetch + LDS-transpose epilogue.
__global__ __launch_bounds__(256) void gemm_qkv(
    const float* __restrict__ X, const _Float16* __restrict__ Wpk,
    _Float16* __restrict__ Yt) {
  __shared__ _Float16 Bs[2][128 * 40];  // 20480 B; epilogue reuses as [64][132] f16 (16896 B)
  const int orig = blockIdx.x;          // 1536 blocks, 1536 % 8 == 0
  const int swz = (orig & 7) * 192 + (orig >> 3);
  const int mt = swz % 3;
  const int nb = swz / 3;
  const int n0 = (nb & 31) << 7;
  const int b  = nb >> 5;
  const float* Xb = X + (size_t)b * CIN * NN;
  _Float16* Yb = Yt + (size_t)b * NN * O3;
  const int tid = threadIdx.x, l = tid & 63, wid = tid >> 6;
  const int wm = (wid >> 1) << 6, wn = (wid & 1) << 6;
  const int fr = l & 15, q = l >> 4;
  const int b_n = (tid & 31) << 2, b_kk = (tid >> 5) << 2;
  const int am16 = mt * 8 + (wm >> 4);
  // write-side swizzle: rows r = b_n+j share r>>2 = tid&31 (j<4)
  const int tp = tid & 31;
  const int swz3 = ((tp ^ (tp >> 2)) & 3) << 1;           // even, 3-bit
  const int gw4 = (((tid >> 5) ^ swz3) << 2);             // f16 offset of swizzled 8B granule
  // read-side swizzle: per-fn offsets, loop-invariant
  int roff[4];
#pragma unroll
  for (int fn = 0; fn < 4; fn++) {
    const int R = wn + fn * 16 + fr;
    const int sR = ((R >> 2) ^ (R >> 4)) & 3;
    roff[fn] = R * 40 + ((q ^ sR) << 3);                  // f16 units, 16B aligned
  }

#define LOADX(dst, t_) do { \
    _Pragma("unroll") \
    for (int r_ = 0; r_ < 4; r_++) \
      dst[r_] = *(const f32x4*)(Xb + (size_t)((t_) * 32 + b_kk + r_) * NN + n0 + b_n); \
  } while (0)
#define LOADAH(dst, t_) do { \
    _Pragma("unroll") \
    for (int fm_ = 0; fm_ < 4; fm_++) \
      dst[fm_] = *(const f16x8*)(Wpk + ((size_t)((am16 + fm_) * 8 + (t_)) * 64 + l) * 8); \
  } while (0)
#define CVTW(buf_, src) do { \
    _Pragma("unroll") \
    for (int j_ = 0; j_ < 4; j_++) { \
      f16x2 p0_ = pkrtz(src[0][j_], src[1][j_]); \
      f16x2 p1_ = pkrtz(src[2][j_], src[3][j_]); \
      *(f16x4*)&Bs[buf_][(b_n + j_) * 40 + gw4] = (f16x4){p0_[0], p0_[1], p1_[0], p1_[1]}; \
    } } while (0)

  f32x4 xr[3][4];                     // 3-deep rotation: X chunk in flight 2 k-steps
  f16x8 ah[2][4];
  f32x4 acc[4][4];
#pragma unroll
  for (int i = 0; i < 4; i++)
#pragma unroll
    for (int j = 0; j < 4; j++) acc[i][j] = (f32x4){0.f, 0.f, 0.f, 0.f};

  // prologue: chunk0 -> Bs[0]; issue ah(0), chunk1, chunk2 (stay in flight across barrier)
  LOADX(xr[0], 0);
  CVTW(0, xr[0]);
  LOADAH(ah[0], 0);
  LOADX(xr[1], 1);
  LOADX(xr[2], 2);
  asm volatile("s_waitcnt lgkmcnt(0)" ::: "memory");
  __builtin_amdgcn_s_barrier();
  __builtin_amdgcn_sched_barrier(0);

#pragma unroll
  for (int t = 0; t < 8; t++) {
    const int cur = t & 1, nxt = cur ^ 1;
    f16x8 bh[4];
#pragma unroll
    for (int fn = 0; fn < 4; fn++)
      bh[fn] = *(const f16x8*)&Bs[cur][roff[fn]];
#pragma unroll
    for (int fm = 0; fm < 4; fm++)
#pragma unroll
      for (int fn = 0; fn < 4; fn++)
        acc[fm][fn] = __builtin_amdgcn_mfma_f32_16x16x32_f16(ah[cur][fm], bh[fn], acc[fm][fn], 0, 0, 0);
    if (t < 7) {
      CVTW(nxt, xr[(t + 1) % 3]);   // chunk t+1, issued 2+ k-steps ago
      LOADAH(ah[nxt], t + 1);       // issue next Wpk frags (L2, 1-step flight)
      if (t < 5) LOADX(xr[(t + 3) % 3], t + 3);  // FIFO: ah-wait forces only this iter's X
    }
    asm volatile("s_waitcnt lgkmcnt(0)" ::: "memory");
    __builtin_amdgcn_s_barrier();
    __builtin_amdgcn_sched_barrier(0);
  }

  // ---- LDS-transpose epilogue: 2 passes of 64 n-rows, coalesced f16x8 stores ----
  _Float16* Ep = &Bs[0][0];           // [64][132] f16, 16896 B, aliases staging buffer
  const int st_n = tid >> 4;          // 0..15
  const int st_m8 = (tid & 15) * 8;   // 0..120
#pragma unroll
  for (int p = 0; p < 2; p++) {
    if ((wid & 1) == p) {             // waves with wn == p*64 hold rows n_local = fn*16+fr
#pragma unroll
      for (int fm = 0; fm < 4; fm++) {
        const int ml = wm + fm * 16 + q * 4;
#pragma unroll
        for (int fn = 0; fn < 4; fn++) {
          const int nl = fn * 16 + fr;
          f16x2 h0 = pkrtz(acc[fm][fn][0], acc[fm][fn][1]);
          f16x2 h1 = pkrtz(acc[fm][fn][2], acc[fm][fn][3]);
          *(f16x4*)&Ep[nl * 132 + ml] = (f16x4){h0[0], h0[1], h1[0], h1[1]};
        }
      }
    }
    __syncthreads();
#pragma unroll
    for (int s = 0; s < 4; s++) {
      const int nl = s * 16 + st_n;
      f16x4 lo = *(const f16x4*)&Ep[nl * 132 + st_m8];
      f16x4 hi = *(const f16x4*)&Ep[nl * 132 + st_m8 + 4];
      f16x8 v = (f16x8){lo[0], lo[1], lo[2], lo[3], hi[0], hi[1], hi[2], hi[3]};
      *(f16x8*)(Yb + (size_t)(n0 + p * 64 + nl) * O3 + mt * 128 + st_m8) = v;
    }
    if (p == 0) __syncthreads();      // protect buffer reuse for pass 1
  }
#undef LOADX
#undef LOADAH
#undef CVTW
}

// ---------------- attn1: exp(K)·V^T outer product + row sums ----------------
// grid (NHEAD, 16, 16), block 256 (4 waves); qkvt layout [n][384].
// v13 change: ns split 8 -> 16 (4 chunks/block instead of 8) -- attn1 is a 512-block
// barrier-locked serial loop (2 blocks/CU, latency-exposed); doubling resident
// parallelism at unchanged traffic. Atomic contention 16 -> 32 contenders per (b,h),
// distinct-address f32 adds absorbed by L2.
__global__ __launch_bounds__(256) void attn1(
    const _Float16* __restrict__ qkvt, float* __restrict__ ctx_raw,
    float* __restrict__ srow_raw) {
  const int h = blockIdx.x, b = blockIdx.y, ns = blockIdx.z;
  const _Float16* base = qkvt + (size_t)b * NN * O3;
  const _Float16* Kb = base + HID + h * DH;
  const _Float16* Vb = base + 2 * HID + h * DH;
  float* ctx = ctx_raw + (size_t)(b * NHEAD + h) * (DH * DH);
  float* srow = srow_raw + (size_t)(b * NHEAD + h) * DH;
  __shared__ __align__(16) float Es[64][36];
  __shared__ __align__(16) float Vs[64][36];
  __shared__ float ctxs[DH][DH + 1];
  __shared__ float srow_s[DH];
  const int tid = threadIdx.x, l = tid & 63, w = tid >> 6;
  const int d4 = (l >> 3) << 2, e4 = (l & 7) << 2;
  if (tid < DH) srow_s[tid] = 0.f;
  for (int i = tid; i < DH * (DH + 1); i += 256) (&ctxs[0][0])[i] = 0.f;
  float sacc[4] = {0.f, 0.f, 0.f, 0.f};
  float acc[4][4];
#pragma unroll
  for (int i = 0; i < 4; i++)
#pragma unroll
    for (int j = 0; j < 4; j++) acc[i][j] = 0.f;

  for (int c = 0; c < 4; c++) {
    const int n0 = ns * 256 + c * 64;
    const size_t roff = (size_t)(n0 + l) * O3 + w * 8;
    f16x8 kv = *(const f16x8*)(Kb + roff);
    f16x8 vv = *(const f16x8*)(Vb + roff);
    __syncthreads();
    float4 e0, e1, v0, v1;
    e0.x = __expf((float)kv[0]); e0.y = __expf((float)kv[1]);
    e0.z = __expf((float)kv[2]); e0.w = __expf((float)kv[3]);
    e1.x = __expf((float)kv[4]); e1.y = __expf((float)kv[5]);
    e1.z = __expf((float)kv[6]); e1.w = __expf((float)kv[7]);
    v0.x = (float)vv[0]; v0.y = (float)vv[1]; v0.z = (float)vv[2]; v0.w = (float)vv[3];
    v1.x = (float)vv[4]; v1.y = (float)vv[5]; v1.z = (float)vv[6]; v1.w = (float)vv[7];
    *(float4*)&Es[l][w * 8] = e0;
    *(float4*)&Es[l][w * 8 + 4] = e1;
    *(float4*)&Vs[l][w * 8] = v0;
    *(float4*)&Vs[l][w * 8 + 4] = v1;
    __syncthreads();
#pragma unroll
    for (int it = 0; it < 16; it++) {
      const int n = w + 4 * it;
      float ka[4], va[4];
      *(float4*)ka = *(const float4*)&Es[n][d4];
      *(float4*)va = *(const float4*)&Vs[n][e4];
#pragma unroll
      for (int i = 0; i < 4; i++) {
        sacc[i] += ka[i];
#pragma unroll
        for (int j = 0; j < 4; j++) acc[i][j] = fmaf(ka[i], va[j], acc[i][j]);
      }
    }
  }
  // srow: sacc identical across the 8 lanes sharing d4 within a wave -> one contributes
  if ((l & 7) == 0) {
#pragma unroll
    for (int i = 0; i < 4; i++) atomicAdd(&srow_s[d4 + i], sacc[i]);
  }
#pragma unroll
  for (int i = 0; i < 4; i++)
#pragma unroll
    for (int j = 0; j < 4; j++) atomicAdd(&ctxs[d4 + i][e4 + j], acc[i][j]);
  __syncthreads();
  for (int i = tid; i < DH * DH; i += 256) atomicAdd(&ctx[i], ctxs[i >> 5][i & 31]);
  if (tid < DH) atomicAdd(&srow[tid], srow_s[tid]);
}

// ---------------- attn2: thread-per-column q-softmax + out = ctx^T q, in-place f16 ----------------
// grid (16, NHEAD, 16), block 256
__global__ __launch_bounds__(256) void attn2(
    _Float16* __restrict__ qkvt, const float* __restrict__ ctx_raw,
    const float* __restrict__ srow_raw) {
  const int ns = blockIdx.x, h = blockIdx.y, b = blockIdx.z;
  const float* cg = ctx_raw + (size_t)(b * NHEAD + h) * (DH * DH);
  const float* sr = srow_raw + (size_t)(b * NHEAD + h) * DH;
  __shared__ float ctxs[DH][DH + 1];
  const int tid = threadIdx.x;
  for (int i = tid; i < DH * DH; i += 256) ctxs[i >> 5][i & 31] = cg[i] / sr[i >> 5];
  __syncthreads();
  const int n = ns * 256 + tid;
  _Float16* qp = qkvt + ((size_t)b * NN + n) * O3 + h * DH;
  float qv[DH];
#pragma unroll
  for (int i = 0; i < 4; i++) {
    f16x8 v = *(const f16x8*)(qp + i * 8);
#pragma unroll
    for (int j = 0; j < 8; j++) qv[i * 8 + j] = (float)v[j];
  }
  float m = -1e30f;
#pragma unroll
  for (int d = 0; d < DH; d++) m = fmaxf(m, qv[d]);
  float s = 0.f;
#pragma unroll
  for (int d = 0; d < DH; d++) { qv[d] = __expf(qv[d] - m); s += qv[d]; }
  float inv = 0.17677669529663687f / s;  // scale = 32^-0.5
#pragma unroll
  for (int d = 0; d < DH; d++) qv[d] *= inv;
#pragma unroll
  for (int eo = 0; eo < 4; eo++) {
    float o[8];
#pragma unroll
    for (int j = 0; j < 8; j++) o[j] = 0.f;
#pragma unroll
    for (int d = 0; d < DH; d++) {
      float qd = qv[d];
#pragma unroll
      for (int j = 0; j < 8; j++) o[j] = fmaf(ctxs[d][eo * 8 + j], qd, o[j]);
    }
    f16x2 h0 = pkrtz(o[0], o[1]);
    f16x2 h1 = pkrtz(o[2], o[3]);
    f16x2 h2 = pkrtz(o[4], o[5]);
    f16x2 h3 = pkrtz(o[6], o[7]);
    f16x8 ov = (f16x8){h0[0], h0[1], h1[0], h1[1], h2[0], h2[1], h3[0], h3[1]};
    *(f16x8*)(qp + eo * 8) = ov;
  }
}

// ---------------- proj pass 1: GEMM (no store) -> GN stats only ----------------
// grid (2, 32, 16), block 256.
__global__ __launch_bounds__(256) void proj_stats(
    const _Float16* __restrict__ At, const _Float16* __restrict__ Wpk,
    const float* __restrict__ bias, double* __restrict__ stats) {
  __shared__ _Float16 Bs[128][40];
  const int mt = blockIdx.x;
  const int n0 = blockIdx.y * 128;
  const int b = blockIdx.z;
  const _Float16* Ab = At + (size_t)b * NN * O3;
  const int tid = threadIdx.x, l = tid & 63, wid = tid >> 6;
  const int wm = (wid >> 1) << 6, wn = (wid & 1) << 6;
  const int fr = l & 15, q = l >> 4, kq = q << 3;
  const int am16 = mt * 8 + (wm >> 4);
  const int sr0 = tid >> 2, sc = (tid & 3) << 3;   // rows 0..63, cols {0,8,16,24}

  f32x4 acc[4][4];
#pragma unroll
  for (int i = 0; i < 4; i++)
#pragma unroll
    for (int j = 0; j < 4; j++) acc[i][j] = (f32x4){0.f, 0.f, 0.f, 0.f};

  for (int k0 = 0; k0 < HID; k0 += 32) {
    f16x8 v0 = *(const f16x8*)(Ab + (size_t)(n0 + sr0) * O3 + k0 + sc);
    f16x8 v1 = *(const f16x8*)(Ab + (size_t)(n0 + 64 + sr0) * O3 + k0 + sc);
    f16x8 ah[4];
#pragma unroll
    for (int fm = 0; fm < 4; fm++)
      ah[fm] = *(const f16x8*)(Wpk + ((size_t)((am16 + fm) * 4 + (k0 >> 5)) * 64 + l) * 8);
    __syncthreads();
    *(f16x8*)&Bs[sr0][sc] = v0;
    *(f16x8*)&Bs[64 + sr0][sc] = v1;
    __syncthreads();
    f16x8 bh[4];
#pragma unroll
    for (int fn = 0; fn < 4; fn++)
      bh[fn] = *(const f16x8*)&Bs[wn + fn * 16 + fr][kq];
#pragma unroll
    for (int fm = 0; fm < 4; fm++)
#pragma unroll
      for (int fn = 0; fn < 4; fn++)
        acc[fm][fn] = __builtin_amdgcn_mfma_f32_16x16x32_f16(ah[fm], bh[fn], acc[fm][fn], 0, 0, 0);
  }
  float lsum = 0.f, lsq = 0.f;
#pragma unroll
  for (int fm = 0; fm < 4; fm++) {
    int rowb = mt * 128 + wm + fm * 16 + q * 4;
#pragma unroll
    for (int r = 0; r < 4; r++) {
      float bv = bias[rowb + r];
#pragma unroll
      for (int fn = 0; fn < 4; fn++) {
        float v = acc[fm][fn][r] + bv;
        lsum += v;
        lsq += v * v;
      }
    }
  }
  double ds = (double)lsum, dq = (double)lsq;
#pragma unroll
  for (int off = 32; off; off >>= 1) {
    ds += __shfl_down(ds, off);
    dq += __shfl_down(dq, off);
  }
  __shared__ double sred[8];
  if (l == 0) { sred[wid] = ds; sred[4 + wid] = dq; }
  __syncthreads();
  if (tid == 0) {
    atomicAdd(&stats[b * 2 + 0], sred[0] + sred[1] + sred[2] + sred[3]);
    atomicAdd(&stats[b * 2 + 1], sred[4] + sred[5] + sred[6] + sred[7]);
  }
}

// ---------------- proj pass 2: recompute GEMM, write normalized out ----------------
// grid (2, 32, 16), block 256.
__global__ __launch_bounds__(256) void proj_write(
    const _Float16* __restrict__ At, const _Float16* __restrict__ Wpk,
    const float* __restrict__ bias, float* __restrict__ out,
    const double* __restrict__ stats, const float* __restrict__ gamma,
    const float* __restrict__ beta) {
  __shared__ _Float16 Bs[128][40];
  const int mt = blockIdx.x;
  const int n0 = blockIdx.y * 128;
  const int b = blockIdx.z;
  const _Float16* Ab = At + (size_t)b * NN * O3;
  float* outb = out + (size_t)b * CIN * NN;
  const int tid = threadIdx.x, l = tid & 63, wid = tid >> 6;
  const int wm = (wid >> 1) << 6, wn = (wid & 1) << 6;
  const int fr = l & 15, q = l >> 4, kq = q << 3;
  const int am16 = mt * 8 + (wm >> 4);
  const int sr0 = tid >> 2, sc = (tid & 3) << 3;   // rows 0..63, cols {0,8,16,24}

  const double nels = (double)CIN * (double)NN;
  double S = stats[b * 2 + 0], Q2 = stats[b * 2 + 1];
  double mu = S / nels;
  double var = Q2 / nels - mu * mu;
  const float mean = (float)mu;
  const float rstd = (float)rsqrt(var + 1e-5);

  f32x4 acc[4][4];
#pragma unroll
  for (int i = 0; i < 4; i++)
#pragma unroll
    for (int j = 0; j < 4; j++) acc[i][j] = (f32x4){0.f, 0.f, 0.f, 0.f};

  for (int k0 = 0; k0 < HID; k0 += 32) {
    f16x8 v0 = *(const f16x8*)(Ab + (size_t)(n0 + sr0) * O3 + k0 + sc);
    f16x8 v1 = *(const f16x8*)(Ab + (size_t)(n0 + 64 + sr0) * O3 + k0 + sc);
    f16x8 ah[4];
#pragma unroll
    for (int fm = 0; fm < 4; fm++)
      ah[fm] = *(const f16x8*)(Wpk + ((size_t)((am16 + fm) * 4 + (k0 >> 5)) * 64 + l) * 8);
    __syncthreads();
    *(f16x8*)&Bs[sr0][sc] = v0;
    *(f16x8*)&Bs[64 + sr0][sc] = v1;
    __syncthreads();
    f16x8 bh[4];
#pragma unroll
    for (int fn = 0; fn < 4; fn++)
      bh[fn] = *(const f16x8*)&Bs[wn + fn * 16 + fr][kq];
#pragma unroll
    for (int fm = 0; fm < 4; fm++)
#pragma unroll
      for (int fn = 0; fn < 4; fn++)
        acc[fm][fn] = __builtin_amdgcn_mfma_f32_16x16x32_f16(ah[fm], bh[fn], acc[fm][fn], 0, 0, 0);
  }
#pragma unroll
  for (int fm = 0; fm < 4; fm++) {
    int rowb = mt * 128 + wm + fm * 16 + q * 4;
#pragma unroll
    for (int r = 0; r < 4; r++) {
      int row = rowb + r;
      float bv = bias[row];
      float g = gamma[row] * rstd, bt = beta[row];
      float* dst = outb + (size_t)row * NN + n0 + wn + fr;
#pragma unroll
      for (int fn = 0; fn < 4; fn++) {
        float v = acc[fm][fn][r] + bv;
        dst[fn * 16] = (v - mean) * g + bt;
      }
    }
  }
}

extern "C" void kernel_launch(void* const* d_in, const int* in_sizes, int n_in,
                              void* d_out, int out_size, void* d_ws, size_t ws_size,
                              hipStream_t stream) {
  const float* x     = (const float*)d_in[0];
  const float* Wqkv  = (const float*)d_in[1];
  const float* Wout  = (const float*)d_in[2];
  const float* bout  = (const float*)d_in[3];
  const float* gamma = (const float*)d_in[4];
  const float* beta  = (const float*)d_in[5];
  float* out = (float*)d_out;

  char* ws = (char*)d_ws;
  _Float16* qkvt = (_Float16*)ws;                             // [16][4096][384] f16
  size_t off = (size_t)16 * NN * O3 * 2;                      // 50331648 B
  _Float16* WpkA = (_Float16*)(ws + off); off += 48 * 256 * 8 * 2;   // 196608 B
  _Float16* WpkB = (_Float16*)(ws + off); off += 16 * 256 * 8 * 2;   // 65536 B
  float* ctxg = (float*)(ws + off); off += (size_t)16 * NHEAD * DH * DH * 4;
  float* srow = (float*)(ws + off); off += (size_t)16 * NHEAD * DH * 4;
  double* stats = (double*)(ws + off);

  const int nz = 16 * NHEAD * DH * DH + 16 * NHEAD * DH + 64;
  prep<<<64 + (nz + 255) / 256, 256, 0, stream>>>(Wqkv, Wout, WpkA, WpkB, ctxg, nz);
  gemm_qkv<<<dim3(1536), 256, 0, stream>>>(x, WpkA, qkvt);
  attn1<<<dim3(NHEAD, 16, 16), 256, 0, stream>>>(qkvt, ctxg, srow);
  attn2<<<dim3(16, NHEAD, 16), 256, 0, stream>>>(qkvt, ctxg, srow);
  proj_stats<<<dim3(2, 32, 16), 256, 0, stream>>>(qkvt, WpkB, bout, stats);
  proj_write<<<dim3(2, 32, 16), 256, 0, stream>>>(qkvt, WpkB, bout, out, stats, gamma, beta);
}

// Round 13
// 122.410 us; speedup vs baseline: 1.1696x; 1.0481x over previous
//
#include <hip/hip_runtime.h>

#define NN 4096
#define CIN 256
#define O3 384
#define HID 128
#define NHEAD 4
#define DH 32

typedef float f32x4 __attribute__((ext_vector_type(4)));
typedef _Float16 f16x8 __attribute__((ext_vector_type(8)));
typedef _Float16 f16x4 __attribute__((ext_vector_type(4)));
typedef _Float16 f16x2 __attribute__((ext_vector_type(2)));
typedef __fp16 fp16x2_raw __attribute__((ext_vector_type(2)));

__device__ __forceinline__ f16x2 pkrtz(float a, float b) {
  fp16x2_raw r = __builtin_amdgcn_cvt_pkrtz(a, b);
  return __builtin_bit_cast(f16x2, r);
}

// ---------------- prepass: pack W into MFMA A-frag layout (f16), zero stats ----------------
// Wpk layout: [(m16*K32 + k32)*64 + l] -> f16x8 : row = m16*16 + (l&15), k = k32*32 + (l>>4)*8 + j
__global__ __launch_bounds__(256) void prep(
    const float* __restrict__ Wqkv, const float* __restrict__ Wout,
    _Float16* __restrict__ WpkA, _Float16* __restrict__ WpkB,
    float* __restrict__ zbase, int nz) {
  const int bid = blockIdx.x, tid = threadIdx.x;
  if (bid < 48) {                       // Wqkv: 24 m16 * 8 k32 * 64 = 12288 threads
    int t = bid * 256 + tid;
    int l = t & 63, mk = t >> 6;
    int k32 = mk & 7, m16 = mk >> 3;
    int row = m16 * 16 + (l & 15), k = k32 * 32 + (l >> 4) * 8;
    const float* s = Wqkv + (size_t)row * CIN + k;
    f16x8 o;
#pragma unroll
    for (int j = 0; j < 8; j++) o[j] = (_Float16)s[j];
    *(f16x8*)(WpkA + (size_t)t * 8) = o;
  } else if (bid < 64) {                // Wout: 16 m16 * 4 k32 * 64 = 4096 threads
    int t = (bid - 48) * 256 + tid;
    int l = t & 63, mk = t >> 6;
    int k32 = mk & 3, m16 = mk >> 2;
    int row = m16 * 16 + (l & 15), k = k32 * 32 + (l >> 4) * 8;
    const float* s = Wout + (size_t)row * HID + k;
    f16x8 o;
#pragma unroll
    for (int j = 0; j < 8; j++) o[j] = (_Float16)s[j];
    *(f16x8*)(WpkB + (size_t)t * 8) = o;
  } else {
    int i = (bid - 64) * 256 + tid;
    if (i < nz) zbase[i] = 0.f;
  }
}

// ---------------- GEMM1: qkvt[b][n][o] = (Wqkv @ X[b])^T, f16 out ----------------
// v10 (proven 44-47us): v6 k-loop + 3-deep X prefetch + LDS-transpose epilogue. Unchanged.
__global__ __launch_bounds__(256) void gemm_qkv(
    const float* __restrict__ X, const _Float16* __restrict__ Wpk,
    _Float16* __restrict__ Yt) {
  __shared__ _Float16 Bs[2][128 * 40];  // 20480 B; epilogue reuses as [64][132] f16 (16896 B)
  const int orig = blockIdx.x;          // 1536 blocks, 1536 % 8 == 0
  const int swz = (orig & 7) * 192 + (orig >> 3);
  const int mt = swz % 3;
  const int nb = swz / 3;
  const int n0 = (nb & 31) << 7;
  const int b  = nb >> 5;
  const float* Xb = X + (size_t)b * CIN * NN;
  _Float16* Yb = Yt + (size_t)b * NN * O3;
  const int tid = threadIdx.x, l = tid & 63, wid = tid >> 6;
  const int wm = (wid >> 1) << 6, wn = (wid & 1) << 6;
  const int fr = l & 15, q = l >> 4;
  const int b_n = (tid & 31) << 2, b_kk = (tid >> 5) << 2;
  const int am16 = mt * 8 + (wm >> 4);
  // write-side swizzle: rows r = b_n+j share r>>2 = tid&31 (j<4)
  const int tp = tid & 31;
  const int swz3 = ((tp ^ (tp >> 2)) & 3) << 1;           // even, 3-bit
  const int gw4 = (((tid >> 5) ^ swz3) << 2);             // f16 offset of swizzled 8B granule
  // read-side swizzle: per-fn offsets, loop-invariant
  int roff[4];
#pragma unroll
  for (int fn = 0; fn < 4; fn++) {
    const int R = wn + fn * 16 + fr;
    const int sR = ((R >> 2) ^ (R >> 4)) & 3;
    roff[fn] = R * 40 + ((q ^ sR) << 3);                  // f16 units, 16B aligned
  }

#define LOADX(dst, t_) do { \
    _Pragma("unroll") \
    for (int r_ = 0; r_ < 4; r_++) \
      dst[r_] = *(const f32x4*)(Xb + (size_t)((t_) * 32 + b_kk + r_) * NN + n0 + b_n); \
  } while (0)
#define LOADAH(dst, t_) do { \
    _Pragma("unroll") \
    for (int fm_ = 0; fm_ < 4; fm_++) \
      dst[fm_] = *(const f16x8*)(Wpk + ((size_t)((am16 + fm_) * 8 + (t_)) * 64 + l) * 8); \
  } while (0)
#define CVTW(buf_, src) do { \
    _Pragma("unroll") \
    for (int j_ = 0; j_ < 4; j_++) { \
      f16x2 p0_ = pkrtz(src[0][j_], src[1][j_]); \
      f16x2 p1_ = pkrtz(src[2][j_], src[3][j_]); \
      *(f16x4*)&Bs[buf_][(b_n + j_) * 40 + gw4] = (f16x4){p0_[0], p0_[1], p1_[0], p1_[1]}; \
    } } while (0)

  f32x4 xr[3][4];                     // 3-deep rotation: X chunk in flight 2 k-steps
  f16x8 ah[2][4];
  f32x4 acc[4][4];
#pragma unroll
  for (int i = 0; i < 4; i++)
#pragma unroll
    for (int j = 0; j < 4; j++) acc[i][j] = (f32x4){0.f, 0.f, 0.f, 0.f};

  // prologue: chunk0 -> Bs[0]; issue ah(0), chunk1, chunk2 (stay in flight across barrier)
  LOADX(xr[0], 0);
  CVTW(0, xr[0]);
  LOADAH(ah[0], 0);
  LOADX(xr[1], 1);
  LOADX(xr[2], 2);
  asm volatile("s_waitcnt lgkmcnt(0)" ::: "memory");
  __builtin_amdgcn_s_barrier();
  __builtin_amdgcn_sched_barrier(0);

#pragma unroll
  for (int t = 0; t < 8; t++) {
    const int cur = t & 1, nxt = cur ^ 1;
    f16x8 bh[4];
#pragma unroll
    for (int fn = 0; fn < 4; fn++)
      bh[fn] = *(const f16x8*)&Bs[cur][roff[fn]];
#pragma unroll
    for (int fm = 0; fm < 4; fm++)
#pragma unroll
      for (int fn = 0; fn < 4; fn++)
        acc[fm][fn] = __builtin_amdgcn_mfma_f32_16x16x32_f16(ah[cur][fm], bh[fn], acc[fm][fn], 0, 0, 0);
    if (t < 7) {
      CVTW(nxt, xr[(t + 1) % 3]);   // chunk t+1, issued 2+ k-steps ago
      LOADAH(ah[nxt], t + 1);       // issue next Wpk frags (L2, 1-step flight)
      if (t < 5) LOADX(xr[(t + 3) % 3], t + 3);  // FIFO: ah-wait forces only this iter's X
    }
    asm volatile("s_waitcnt lgkmcnt(0)" ::: "memory");
    __builtin_amdgcn_s_barrier();
    __builtin_amdgcn_sched_barrier(0);
  }

  // ---- LDS-transpose epilogue: 2 passes of 64 n-rows, coalesced f16x8 stores ----
  _Float16* Ep = &Bs[0][0];           // [64][132] f16, 16896 B, aliases staging buffer
  const int st_n = tid >> 4;          // 0..15
  const int st_m8 = (tid & 15) * 8;   // 0..120
#pragma unroll
  for (int p = 0; p < 2; p++) {
    if ((wid & 1) == p) {             // waves with wn == p*64 hold rows n_local = fn*16+fr
#pragma unroll
      for (int fm = 0; fm < 4; fm++) {
        const int ml = wm + fm * 16 + q * 4;
#pragma unroll
        for (int fn = 0; fn < 4; fn++) {
          const int nl = fn * 16 + fr;
          f16x2 h0 = pkrtz(acc[fm][fn][0], acc[fm][fn][1]);
          f16x2 h1 = pkrtz(acc[fm][fn][2], acc[fm][fn][3]);
          *(f16x4*)&Ep[nl * 132 + ml] = (f16x4){h0[0], h0[1], h1[0], h1[1]};
        }
      }
    }
    __syncthreads();
#pragma unroll
    for (int s = 0; s < 4; s++) {
      const int nl = s * 16 + st_n;
      f16x4 lo = *(const f16x4*)&Ep[nl * 132 + st_m8];
      f16x4 hi = *(const f16x4*)&Ep[nl * 132 + st_m8 + 4];
      f16x8 v = (f16x8){lo[0], lo[1], lo[2], lo[3], hi[0], hi[1], hi[2], hi[3]};
      *(f16x8*)(Yb + (size_t)(n0 + p * 64 + nl) * O3 + mt * 128 + st_m8) = v;
    }
    if (p == 0) __syncthreads();      // protect buffer reuse for pass 1
  }
#undef LOADX
#undef LOADAH
#undef CVTW
}

// ---------------- attn1: exp(K)·V^T outer product + row sums -> PER-BLOCK PARTIALS ----------------
// grid (NHEAD, 16, 8), block 256 (4 waves); qkvt layout [n][384].
// v14 change (sole change vs v10): the end-of-block global atomicAdd reduction (1024 f32 RMW
// per block, 524K total -- the confirmed ~5-8us cost per v13's 2x-atomics regression) is
// replaced by plain coalesced stores into a private partial slot [b][h][ns]; attn2 sums the
// 8 partials (L2-hot, 2MB total).
__global__ __launch_bounds__(256) void attn1(
    const _Float16* __restrict__ qkvt, float* __restrict__ ctxp,
    float* __restrict__ srowp) {
  const int h = blockIdx.x, b = blockIdx.y, ns = blockIdx.z;
  const _Float16* base = qkvt + (size_t)b * NN * O3;
  const _Float16* Kb = base + HID + h * DH;
  const _Float16* Vb = base + 2 * HID + h * DH;
  __shared__ __align__(16) float Es[64][36];
  __shared__ __align__(16) float Vs[64][36];
  __shared__ float ctxs[DH][DH + 1];
  __shared__ float srow_s[DH];
  const int tid = threadIdx.x, l = tid & 63, w = tid >> 6;
  const int d4 = (l >> 3) << 2, e4 = (l & 7) << 2;
  if (tid < DH) srow_s[tid] = 0.f;
  for (int i = tid; i < DH * (DH + 1); i += 256) (&ctxs[0][0])[i] = 0.f;
  float sacc[4] = {0.f, 0.f, 0.f, 0.f};
  float acc[4][4];
#pragma unroll
  for (int i = 0; i < 4; i++)
#pragma unroll
    for (int j = 0; j < 4; j++) acc[i][j] = 0.f;

  for (int c = 0; c < 8; c++) {
    const int n0 = ns * 512 + c * 64;
    const size_t roff = (size_t)(n0 + l) * O3 + w * 8;
    f16x8 kv = *(const f16x8*)(Kb + roff);
    f16x8 vv = *(const f16x8*)(Vb + roff);
    __syncthreads();
    float4 e0, e1, v0, v1;
    e0.x = __expf((float)kv[0]); e0.y = __expf((float)kv[1]);
    e0.z = __expf((float)kv[2]); e0.w = __expf((float)kv[3]);
    e1.x = __expf((float)kv[4]); e1.y = __expf((float)kv[5]);
    e1.z = __expf((float)kv[6]); e1.w = __expf((float)kv[7]);
    v0.x = (float)vv[0]; v0.y = (float)vv[1]; v0.z = (float)vv[2]; v0.w = (float)vv[3];
    v1.x = (float)vv[4]; v1.y = (float)vv[5]; v1.z = (float)vv[6]; v1.w = (float)vv[7];
    *(float4*)&Es[l][w * 8] = e0;
    *(float4*)&Es[l][w * 8 + 4] = e1;
    *(float4*)&Vs[l][w * 8] = v0;
    *(float4*)&Vs[l][w * 8 + 4] = v1;
    __syncthreads();
#pragma unroll
    for (int it = 0; it < 16; it++) {
      const int n = w + 4 * it;
      float ka[4], va[4];
      *(float4*)ka = *(const float4*)&Es[n][d4];
      *(float4*)va = *(const float4*)&Vs[n][e4];
#pragma unroll
      for (int i = 0; i < 4; i++) {
        sacc[i] += ka[i];
#pragma unroll
        for (int j = 0; j < 4; j++) acc[i][j] = fmaf(ka[i], va[j], acc[i][j]);
      }
    }
  }
  // srow: sacc identical across the 8 lanes sharing d4 within a wave -> one contributes
  if ((l & 7) == 0) {
#pragma unroll
    for (int i = 0; i < 4; i++) atomicAdd(&srow_s[d4 + i], sacc[i]);
  }
#pragma unroll
  for (int i = 0; i < 4; i++)
#pragma unroll
    for (int j = 0; j < 4; j++) atomicAdd(&ctxs[d4 + i][e4 + j], acc[i][j]);
  __syncthreads();
  // plain coalesced stores to the private partial slot (no global RMW)
  float* cout = ctxp + (((size_t)(b * NHEAD + h)) * 8 + ns) * (DH * DH);
  float* sout = srowp + (((size_t)(b * NHEAD + h)) * 8 + ns) * DH;
  for (int i = tid; i < DH * DH; i += 256) cout[i] = ctxs[i >> 5][i & 31];
  if (tid < DH) sout[tid] = srow_s[tid];
}

// ---------------- attn2: sum 8 partials, thread-per-column q-softmax + out = ctx^T q ----------------
// grid (16, NHEAD, 16), block 256
__global__ __launch_bounds__(256) void attn2(
    _Float16* __restrict__ qkvt, const float* __restrict__ ctxp,
    const float* __restrict__ srowp) {
  const int ns = blockIdx.x, h = blockIdx.y, b = blockIdx.z;
  const float* cg = ctxp + ((size_t)(b * NHEAD + h)) * 8 * (DH * DH);
  const float* sp = srowp + ((size_t)(b * NHEAD + h)) * 8 * DH;
  __shared__ float ctxs[DH][DH + 1];
  __shared__ float srow_l[DH];
  const int tid = threadIdx.x;
  if (tid < DH) {
    float s = 0.f;
#pragma unroll
    for (int p = 0; p < 8; p++) s += sp[p * DH + tid];
    srow_l[tid] = s;
  }
  __syncthreads();
  for (int i = tid; i < DH * DH; i += 256) {
    float c = 0.f;
#pragma unroll
    for (int p = 0; p < 8; p++) c += cg[p * DH * DH + i];
    ctxs[i >> 5][i & 31] = c / srow_l[i >> 5];
  }
  __syncthreads();
  const int n = ns * 256 + tid;
  _Float16* qp = qkvt + ((size_t)b * NN + n) * O3 + h * DH;
  float qv[DH];
#pragma unroll
  for (int i = 0; i < 4; i++) {
    f16x8 v = *(const f16x8*)(qp + i * 8);
#pragma unroll
    for (int j = 0; j < 8; j++) qv[i * 8 + j] = (float)v[j];
  }
  float m = -1e30f;
#pragma unroll
  for (int d = 0; d < DH; d++) m = fmaxf(m, qv[d]);
  float s = 0.f;
#pragma unroll
  for (int d = 0; d < DH; d++) { qv[d] = __expf(qv[d] - m); s += qv[d]; }
  float inv = 0.17677669529663687f / s;  // scale = 32^-0.5
#pragma unroll
  for (int d = 0; d < DH; d++) qv[d] *= inv;
#pragma unroll
  for (int eo = 0; eo < 4; eo++) {
    float o[8];
#pragma unroll
    for (int j = 0; j < 8; j++) o[j] = 0.f;
#pragma unroll
    for (int d = 0; d < DH; d++) {
      float qd = qv[d];
#pragma unroll
      for (int j = 0; j < 8; j++) o[j] = fmaf(ctxs[d][eo * 8 + j], qd, o[j]);
    }
    f16x2 h0 = pkrtz(o[0], o[1]);
    f16x2 h1 = pkrtz(o[2], o[3]);
    f16x2 h2 = pkrtz(o[4], o[5]);
    f16x2 h3 = pkrtz(o[6], o[7]);
    f16x8 ov = (f16x8){h0[0], h0[1], h1[0], h1[1], h2[0], h2[1], h3[0], h3[1]};
    *(f16x8*)(qp + eo * 8) = ov;
  }
}

// ---------------- proj pass 1: GEMM (no store) -> GN stats only ----------------
// grid (2, 32, 16), block 256.
__global__ __launch_bounds__(256) void proj_stats(
    const _Float16* __restrict__ At, const _Float16* __restrict__ Wpk,
    const float* __restrict__ bias, double* __restrict__ stats) {
  __shared__ _Float16 Bs[128][40];
  const int mt = blockIdx.x;
  const int n0 = blockIdx.y * 128;
  const int b = blockIdx.z;
  const _Float16* Ab = At + (size_t)b * NN * O3;
  const int tid = threadIdx.x, l = tid & 63, wid = tid >> 6;
  const int wm = (wid >> 1) << 6, wn = (wid & 1) << 6;
  const int fr = l & 15, q = l >> 4, kq = q << 3;
  const int am16 = mt * 8 + (wm >> 4);
  const int sr0 = tid >> 2, sc = (tid & 3) << 3;   // rows 0..63, cols {0,8,16,24}

  f32x4 acc[4][4];
#pragma unroll
  for (int i = 0; i < 4; i++)
#pragma unroll
    for (int j = 0; j < 4; j++) acc[i][j] = (f32x4){0.f, 0.f, 0.f, 0.f};

  for (int k0 = 0; k0 < HID; k0 += 32) {
    f16x8 v0 = *(const f16x8*)(Ab + (size_t)(n0 + sr0) * O3 + k0 + sc);
    f16x8 v1 = *(const f16x8*)(Ab + (size_t)(n0 + 64 + sr0) * O3 + k0 + sc);
    f16x8 ah[4];
#pragma unroll
    for (int fm = 0; fm < 4; fm++)
      ah[fm] = *(const f16x8*)(Wpk + ((size_t)((am16 + fm) * 4 + (k0 >> 5)) * 64 + l) * 8);
    __syncthreads();
    *(f16x8*)&Bs[sr0][sc] = v0;
    *(f16x8*)&Bs[64 + sr0][sc] = v1;
    __syncthreads();
    f16x8 bh[4];
#pragma unroll
    for (int fn = 0; fn < 4; fn++)
      bh[fn] = *(const f16x8*)&Bs[wn + fn * 16 + fr][kq];
#pragma unroll
    for (int fm = 0; fm < 4; fm++)
#pragma unroll
      for (int fn = 0; fn < 4; fn++)
        acc[fm][fn] = __builtin_amdgcn_mfma_f32_16x16x32_f16(ah[fm], bh[fn], acc[fm][fn], 0, 0, 0);
  }
  float lsum = 0.f, lsq = 0.f;
#pragma unroll
  for (int fm = 0; fm < 4; fm++) {
    int rowb = mt * 128 + wm + fm * 16 + q * 4;
#pragma unroll
    for (int r = 0; r < 4; r++) {
      float bv = bias[rowb + r];
#pragma unroll
      for (int fn = 0; fn < 4; fn++) {
        float v = acc[fm][fn][r] + bv;
        lsum += v;
        lsq += v * v;
      }
    }
  }
  double ds = (double)lsum, dq = (double)lsq;
#pragma unroll
  for (int off = 32; off; off >>= 1) {
    ds += __shfl_down(ds, off);
    dq += __shfl_down(dq, off);
  }
  __shared__ double sred[8];
  if (l == 0) { sred[wid] = ds; sred[4 + wid] = dq; }
  __syncthreads();
  if (tid == 0) {
    atomicAdd(&stats[b * 2 + 0], sred[0] + sred[1] + sred[2] + sred[3]);
    atomicAdd(&stats[b * 2 + 1], sred[4] + sred[5] + sred[6] + sred[7]);
  }
}

// ---------------- proj pass 2: recompute GEMM, write normalized out ----------------
// grid (2, 32, 16), block 256.
__global__ __launch_bounds__(256) void proj_write(
    const _Float16* __restrict__ At, const _Float16* __restrict__ Wpk,
    const float* __restrict__ bias, float* __restrict__ out,
    const double* __restrict__ stats, const float* __restrict__ gamma,
    const float* __restrict__ beta) {
  __shared__ _Float16 Bs[128][40];
  const int mt = blockIdx.x;
  const int n0 = blockIdx.y * 128;
  const int b = blockIdx.z;
  const _Float16* Ab = At + (size_t)b * NN * O3;
  float* outb = out + (size_t)b * CIN * NN;
  const int tid = threadIdx.x, l = tid & 63, wid = tid >> 6;
  const int wm = (wid >> 1) << 6, wn = (wid & 1) << 6;
  const int fr = l & 15, q = l >> 4, kq = q << 3;
  const int am16 = mt * 8 + (wm >> 4);
  const int sr0 = tid >> 2, sc = (tid & 3) << 3;   // rows 0..63, cols {0,8,16,24}

  const double nels = (double)CIN * (double)NN;
  double S = stats[b * 2 + 0], Q2 = stats[b * 2 + 1];
  double mu = S / nels;
  double var = Q2 / nels - mu * mu;
  const float mean = (float)mu;
  const float rstd = (float)rsqrt(var + 1e-5);

  f32x4 acc[4][4];
#pragma unroll
  for (int i = 0; i < 4; i++)
#pragma unroll
    for (int j = 0; j < 4; j++) acc[i][j] = (f32x4){0.f, 0.f, 0.f, 0.f};

  for (int k0 = 0; k0 < HID; k0 += 32) {
    f16x8 v0 = *(const f16x8*)(Ab + (size_t)(n0 + sr0) * O3 + k0 + sc);
    f16x8 v1 = *(const f16x8*)(Ab + (size_t)(n0 + 64 + sr0) * O3 + k0 + sc);
    f16x8 ah[4];
#pragma unroll
    for (int fm = 0; fm < 4; fm++)
      ah[fm] = *(const f16x8*)(Wpk + ((size_t)((am16 + fm) * 4 + (k0 >> 5)) * 64 + l) * 8);
    __syncthreads();
    *(f16x8*)&Bs[sr0][sc] = v0;
    *(f16x8*)&Bs[64 + sr0][sc] = v1;
    __syncthreads();
    f16x8 bh[4];
#pragma unroll
    for (int fn = 0; fn < 4; fn++)
      bh[fn] = *(const f16x8*)&Bs[wn + fn * 16 + fr][kq];
#pragma unroll
    for (int fm = 0; fm < 4; fm++)
#pragma unroll
      for (int fn = 0; fn < 4; fn++)
        acc[fm][fn] = __builtin_amdgcn_mfma_f32_16x16x32_f16(ah[fm], bh[fn], acc[fm][fn], 0, 0, 0);
  }
#pragma unroll
  for (int fm = 0; fm < 4; fm++) {
    int rowb = mt * 128 + wm + fm * 16 + q * 4;
#pragma unroll
    for (int r = 0; r < 4; r++) {
      int row = rowb + r;
      float bv = bias[row];
      float g = gamma[row] * rstd, bt = beta[row];
      float* dst = outb + (size_t)row * NN + n0 + wn + fr;
#pragma unroll
      for (int fn = 0; fn < 4; fn++) {
        float v = acc[fm][fn][r] + bv;
        dst[fn * 16] = (v - mean) * g + bt;
      }
    }
  }
}

extern "C" void kernel_launch(void* const* d_in, const int* in_sizes, int n_in,
                              void* d_out, int out_size, void* d_ws, size_t ws_size,
                              hipStream_t stream) {
  const float* x     = (const float*)d_in[0];
  const float* Wqkv  = (const float*)d_in[1];
  const float* Wout  = (const float*)d_in[2];
  const float* bout  = (const float*)d_in[3];
  const float* gamma = (const float*)d_in[4];
  const float* beta  = (const float*)d_in[5];
  float* out = (float*)d_out;

  char* ws = (char*)d_ws;
  _Float16* qkvt = (_Float16*)ws;                             // [16][4096][384] f16
  size_t off = (size_t)16 * NN * O3 * 2;                      // 50331648 B
  _Float16* WpkA = (_Float16*)(ws + off); off += 48 * 256 * 8 * 2;   // 196608 B
  _Float16* WpkB = (_Float16*)(ws + off); off += 16 * 256 * 8 * 2;   // 65536 B
  float* ctxp = (float*)(ws + off); off += (size_t)16 * NHEAD * 8 * DH * DH * 4;  // 2 MiB partials
  float* srowp = (float*)(ws + off); off += (size_t)16 * NHEAD * 8 * DH * 4;      // 64 KiB partials
  double* stats = (double*)(ws + off);

  prep<<<65, 256, 0, stream>>>(Wqkv, Wout, WpkA, WpkB, (float*)stats, 64);
  gemm_qkv<<<dim3(1536), 256, 0, stream>>>(x, WpkA, qkvt);
  attn1<<<dim3(NHEAD, 16, 8), 256, 0, stream>>>(qkvt, ctxp, srowp);
  attn2<<<dim3(16, NHEAD, 16), 256, 0, stream>>>(qkvt, ctxp, srowp);
  proj_stats<<<dim3(2, 32, 16), 256, 0, stream>>>(qkvt, WpkB, bout, stats);
  proj_write<<<dim3(2, 32, 16), 256, 0, stream>>>(qkvt, WpkB, bout, out, stats, gamma, beta);
}

// Round 14
// 120.081 us; speedup vs baseline: 1.1923x; 1.0194x over previous
//
#include <hip/hip_runtime.h>

#define NN 4096
#define CIN 256
#define O3 384
#define HID 128
#define NHEAD 4
#define DH 32

typedef float f32x4 __attribute__((ext_vector_type(4)));
typedef _Float16 f16x8 __attribute__((ext_vector_type(8)));
typedef _Float16 f16x4 __attribute__((ext_vector_type(4)));
typedef _Float16 f16x2 __attribute__((ext_vector_type(2)));
typedef __fp16 fp16x2_raw __attribute__((ext_vector_type(2)));

__device__ __forceinline__ f16x2 pkrtz(float a, float b) {
  fp16x2_raw r = __builtin_amdgcn_cvt_pkrtz(a, b);
  return __builtin_bit_cast(f16x2, r);
}

// ---------------- prepass: pack W into MFMA A-frag layout (f16), zero scratch ----------------
// Wpk layout: [(m16*K32 + k32)*64 + l] -> f16x8 : row = m16*16 + (l&15), k = k32*32 + (l>>4)*8 + j
__global__ __launch_bounds__(256) void prep(
    const float* __restrict__ Wqkv, const float* __restrict__ Wout,
    _Float16* __restrict__ WpkA, _Float16* __restrict__ WpkB,
    float* __restrict__ zbase, int nz) {
  const int bid = blockIdx.x, tid = threadIdx.x;
  if (bid < 48) {                       // Wqkv: 24 m16 * 8 k32 * 64 = 12288 threads
    int t = bid * 256 + tid;
    int l = t & 63, mk = t >> 6;
    int k32 = mk & 7, m16 = mk >> 3;
    int row = m16 * 16 + (l & 15), k = k32 * 32 + (l >> 4) * 8;
    const float* s = Wqkv + (size_t)row * CIN + k;
    f16x8 o;
#pragma unroll
    for (int j = 0; j < 8; j++) o[j] = (_Float16)s[j];
    *(f16x8*)(WpkA + (size_t)t * 8) = o;
  } else if (bid < 64) {                // Wout: 16 m16 * 4 k32 * 64 = 4096 threads
    int t = (bid - 48) * 256 + tid;
    int l = t & 63, mk = t >> 6;
    int k32 = mk & 3, m16 = mk >> 2;
    int row = m16 * 16 + (l & 15), k = k32 * 32 + (l >> 4) * 8;
    const float* s = Wout + (size_t)row * HID + k;
    f16x8 o;
#pragma unroll
    for (int j = 0; j < 8; j++) o[j] = (_Float16)s[j];
    *(f16x8*)(WpkB + (size_t)t * 8) = o;
  } else {
    int i = (bid - 64) * 256 + tid;
    if (i < nz) zbase[i] = 0.f;
  }
}

// ---------------- GEMM1: qkvt[b][n][o] = (Wqkv @ X[b])^T, f16 out ----------------
// v10 (proven 44-47us): v6 k-loop + 3-deep X prefetch + LDS-transpose epilogue.
__global__ __launch_bounds__(256) void gemm_qkv(
    const float* __restrict__ X, const _Float16* __restrict__ Wpk,
    _Float16* __restrict__ Yt) {
  __shared__ _Float16 Bs[2][128 * 40];  // 20480 B; epilogue reuses as [64][132] f16 (16896 B)
  const int orig = blockIdx.x;          // 1536 blocks, 1536 % 8 == 0
  const int swz = (orig & 7) * 192 + (orig >> 3);
  const int mt = swz % 3;
  const int nb = swz / 3;
  const int n0 = (nb & 31) << 7;
  const int b  = nb >> 5;
  const float* Xb = X + (size_t)b * CIN * NN;
  _Float16* Yb = Yt + (size_t)b * NN * O3;
  const int tid = threadIdx.x, l = tid & 63, wid = tid >> 6;
  const int wm = (wid >> 1) << 6, wn = (wid & 1) << 6;
  const int fr = l & 15, q = l >> 4;
  const int b_n = (tid & 31) << 2, b_kk = (tid >> 5) << 2;
  const int am16 = mt * 8 + (wm >> 4);
  // write-side swizzle: rows r = b_n+j share r>>2 = tid&31 (j<4)
  const int tp = tid & 31;
  const int swz3 = ((tp ^ (tp >> 2)) & 3) << 1;           // even, 3-bit
  const int gw4 = (((tid >> 5) ^ swz3) << 2);             // f16 offset of swizzled 8B granule
  // read-side swizzle: per-fn offsets, loop-invariant
  int roff[4];
#pragma unroll
  for (int fn = 0; fn < 4; fn++) {
    const int R = wn + fn * 16 + fr;
    const int sR = ((R >> 2) ^ (R >> 4)) & 3;
    roff[fn] = R * 40 + ((q ^ sR) << 3);                  // f16 units, 16B aligned
  }

#define LOADX(dst, t_) do { \
    _Pragma("unroll") \
    for (int r_ = 0; r_ < 4; r_++) \
      dst[r_] = *(const f32x4*)(Xb + (size_t)((t_) * 32 + b_kk + r_) * NN + n0 + b_n); \
  } while (0)
#define LOADAH(dst, t_) do { \
    _Pragma("unroll") \
    for (int fm_ = 0; fm_ < 4; fm_++) \
      dst[fm_] = *(const f16x8*)(Wpk + ((size_t)((am16 + fm_) * 8 + (t_)) * 64 + l) * 8); \
  } while (0)
#define CVTW(buf_, src) do { \
    _Pragma("unroll") \
    for (int j_ = 0; j_ < 4; j_++) { \
      f16x2 p0_ = pkrtz(src[0][j_], src[1][j_]); \
      f16x2 p1_ = pkrtz(src[2][j_], src[3][j_]); \
      *(f16x4*)&Bs[buf_][(b_n + j_) * 40 + gw4] = (f16x4){p0_[0], p0_[1], p1_[0], p1_[1]}; \
    } } while (0)

  f32x4 xr[3][4];                     // 3-deep rotation: X chunk in flight 2 k-steps
  f16x8 ah[2][4];
  f32x4 acc[4][4];
#pragma unroll
  for (int i = 0; i < 4; i++)
#pragma unroll
    for (int j = 0; j < 4; j++) acc[i][j] = (f32x4){0.f, 0.f, 0.f, 0.f};

  // prologue: chunk0 -> Bs[0]; issue ah(0), chunk1, chunk2 (stay in flight across barrier)
  LOADX(xr[0], 0);
  CVTW(0, xr[0]);
  LOADAH(ah[0], 0);
  LOADX(xr[1], 1);
  LOADX(xr[2], 2);
  asm volatile("s_waitcnt lgkmcnt(0)" ::: "memory");
  __builtin_amdgcn_s_barrier();
  __builtin_amdgcn_sched_barrier(0);

#pragma unroll
  for (int t = 0; t < 8; t++) {
    const int cur = t & 1, nxt = cur ^ 1;
    f16x8 bh[4];
#pragma unroll
    for (int fn = 0; fn < 4; fn++)
      bh[fn] = *(const f16x8*)&Bs[cur][roff[fn]];
#pragma unroll
    for (int fm = 0; fm < 4; fm++)
#pragma unroll
      for (int fn = 0; fn < 4; fn++)
        acc[fm][fn] = __builtin_amdgcn_mfma_f32_16x16x32_f16(ah[cur][fm], bh[fn], acc[fm][fn], 0, 0, 0);
    if (t < 7) {
      CVTW(nxt, xr[(t + 1) % 3]);   // chunk t+1, issued 2+ k-steps ago
      LOADAH(ah[nxt], t + 1);       // issue next Wpk frags (L2, 1-step flight)
      if (t < 5) LOADX(xr[(t + 3) % 3], t + 3);  // FIFO: ah-wait forces only this iter's X
    }
    asm volatile("s_waitcnt lgkmcnt(0)" ::: "memory");
    __builtin_amdgcn_s_barrier();
    __builtin_amdgcn_sched_barrier(0);
  }

  // ---- LDS-transpose epilogue: 2 passes of 64 n-rows, coalesced f16x8 stores ----
  _Float16* Ep = &Bs[0][0];           // [64][132] f16, 16896 B, aliases staging buffer
  const int st_n = tid >> 4;          // 0..15
  const int st_m8 = (tid & 15) * 8;   // 0..120
#pragma unroll
  for (int p = 0; p < 2; p++) {
    if ((wid & 1) == p) {             // waves with wn == p*64 hold rows n_local = fn*16+fr
#pragma unroll
      for (int fm = 0; fm < 4; fm++) {
        const int ml = wm + fm * 16 + q * 4;
#pragma unroll
        for (int fn = 0; fn < 4; fn++) {
          const int nl = fn * 16 + fr;
          f16x2 h0 = pkrtz(acc[fm][fn][0], acc[fm][fn][1]);
          f16x2 h1 = pkrtz(acc[fm][fn][2], acc[fm][fn][3]);
          *(f16x4*)&Ep[nl * 132 + ml] = (f16x4){h0[0], h0[1], h1[0], h1[1]};
        }
      }
    }
    __syncthreads();
#pragma unroll
    for (int s = 0; s < 4; s++) {
      const int nl = s * 16 + st_n;
      f16x4 lo = *(const f16x4*)&Ep[nl * 132 + st_m8];
      f16x4 hi = *(const f16x4*)&Ep[nl * 132 + st_m8 + 4];
      f16x8 v = (f16x8){lo[0], lo[1], lo[2], lo[3], hi[0], hi[1], hi[2], hi[3]};
      *(f16x8*)(Yb + (size_t)(n0 + p * 64 + nl) * O3 + mt * 128 + st_m8) = v;
    }
    if (p == 0) __syncthreads();      // protect buffer reuse for pass 1
  }
#undef LOADX
#undef LOADAH
#undef CVTW
}

// ---------------- attn1: exp(K)·V^T outer product + row sums ----------------
// grid (NHEAD, 16, 8), block 256 (4 waves); qkvt layout [n][384]
__global__ __launch_bounds__(256) void attn1(
    const _Float16* __restrict__ qkvt, float* __restrict__ ctx_raw,
    float* __restrict__ srow_raw) {
  const int h = blockIdx.x, b = blockIdx.y, ns = blockIdx.z;
  const _Float16* base = qkvt + (size_t)b * NN * O3;
  const _Float16* Kb = base + HID + h * DH;
  const _Float16* Vb = base + 2 * HID + h * DH;
  float* ctx = ctx_raw + (size_t)(b * NHEAD + h) * (DH * DH);
  float* srow = srow_raw + (size_t)(b * NHEAD + h) * DH;
  __shared__ __align__(16) float Es[64][36];
  __shared__ __align__(16) float Vs[64][36];
  __shared__ float ctxs[DH][DH + 1];
  __shared__ float srow_s[DH];
  const int tid = threadIdx.x, l = tid & 63, w = tid >> 6;
  const int d4 = (l >> 3) << 2, e4 = (l & 7) << 2;
  if (tid < DH) srow_s[tid] = 0.f;
  for (int i = tid; i < DH * (DH + 1); i += 256) (&ctxs[0][0])[i] = 0.f;
  float sacc[4] = {0.f, 0.f, 0.f, 0.f};
  float acc[4][4];
#pragma unroll
  for (int i = 0; i < 4; i++)
#pragma unroll
    for (int j = 0; j < 4; j++) acc[i][j] = 0.f;

  for (int c = 0; c < 8; c++) {
    const int n0 = ns * 512 + c * 64;
    const size_t roff = (size_t)(n0 + l) * O3 + w * 8;
    f16x8 kv = *(const f16x8*)(Kb + roff);
    f16x8 vv = *(const f16x8*)(Vb + roff);
    __syncthreads();
    float4 e0, e1, v0, v1;
    e0.x = __expf((float)kv[0]); e0.y = __expf((float)kv[1]);
    e0.z = __expf((float)kv[2]); e0.w = __expf((float)kv[3]);
    e1.x = __expf((float)kv[4]); e1.y = __expf((float)kv[5]);
    e1.z = __expf((float)kv[6]); e1.w = __expf((float)kv[7]);
    v0.x = (float)vv[0]; v0.y = (float)vv[1]; v0.z = (float)vv[2]; v0.w = (float)vv[3];
    v1.x = (float)vv[4]; v1.y = (float)vv[5]; v1.z = (float)vv[6]; v1.w = (float)vv[7];
    *(float4*)&Es[l][w * 8] = e0;
    *(float4*)&Es[l][w * 8 + 4] = e1;
    *(float4*)&Vs[l][w * 8] = v0;
    *(float4*)&Vs[l][w * 8 + 4] = v1;
    __syncthreads();
#pragma unroll
    for (int it = 0; it < 16; it++) {
      const int n = w + 4 * it;
      float ka[4], va[4];
      *(float4*)ka = *(const float4*)&Es[n][d4];
      *(float4*)va = *(const float4*)&Vs[n][e4];
#pragma unroll
      for (int i = 0; i < 4; i++) {
        sacc[i] += ka[i];
#pragma unroll
        for (int j = 0; j < 4; j++) acc[i][j] = fmaf(ka[i], va[j], acc[i][j]);
      }
    }
  }
  // srow: sacc identical across the 8 lanes sharing d4 within a wave -> one contributes
  if ((l & 7) == 0) {
#pragma unroll
    for (int i = 0; i < 4; i++) atomicAdd(&srow_s[d4 + i], sacc[i]);
  }
#pragma unroll
  for (int i = 0; i < 4; i++)
#pragma unroll
    for (int j = 0; j < 4; j++) atomicAdd(&ctxs[d4 + i][e4 + j], acc[i][j]);
  __syncthreads();
  for (int i = tid; i < DH * DH; i += 256) atomicAdd(&ctx[i], ctxs[i >> 5][i & 31]);
  if (tid < DH) atomicAdd(&srow[tid], srow_s[tid]);
}

// ---------------- attn2: thread-per-column q-softmax + out = ctx^T q, in-place f16 ----------------
// grid (16, NHEAD, 16), block 256
__global__ __launch_bounds__(256) void attn2(
    _Float16* __restrict__ qkvt, const float* __restrict__ ctx_raw,
    const float* __restrict__ srow_raw) {
  const int ns = blockIdx.x, h = blockIdx.y, b = blockIdx.z;
  const float* cg = ctx_raw + (size_t)(b * NHEAD + h) * (DH * DH);
  const float* sr = srow_raw + (size_t)(b * NHEAD + h) * DH;
  __shared__ float ctxs[DH][DH + 1];
  const int tid = threadIdx.x;
  for (int i = tid; i < DH * DH; i += 256) ctxs[i >> 5][i & 31] = cg[i] / sr[i >> 5];
  __syncthreads();
  const int n = ns * 256 + tid;
  _Float16* qp = qkvt + ((size_t)b * NN + n) * O3 + h * DH;
  float qv[DH];
#pragma unroll
  for (int i = 0; i < 4; i++) {
    f16x8 v = *(const f16x8*)(qp + i * 8);
#pragma unroll
    for (int j = 0; j < 8; j++) qv[i * 8 + j] = (float)v[j];
  }
  float m = -1e30f;
#pragma unroll
  for (int d = 0; d < DH; d++) m = fmaxf(m, qv[d]);
  float s = 0.f;
#pragma unroll
  for (int d = 0; d < DH; d++) { qv[d] = __expf(qv[d] - m); s += qv[d]; }
  float inv = 0.17677669529663687f / s;  // scale = 32^-0.5
#pragma unroll
  for (int d = 0; d < DH; d++) qv[d] *= inv;
#pragma unroll
  for (int eo = 0; eo < 4; eo++) {
    float o[8];
#pragma unroll
    for (int j = 0; j < 8; j++) o[j] = 0.f;
#pragma unroll
    for (int d = 0; d < DH; d++) {
      float qd = qv[d];
#pragma unroll
      for (int j = 0; j < 8; j++) o[j] = fmaf(ctxs[d][eo * 8 + j], qd, o[j]);
    }
    f16x2 h0 = pkrtz(o[0], o[1]);
    f16x2 h1 = pkrtz(o[2], o[3]);
    f16x2 h2 = pkrtz(o[4], o[5]);
    f16x2 h3 = pkrtz(o[6], o[7]);
    f16x8 ov = (f16x8){h0[0], h0[1], h1[0], h1[1], h2[0], h2[1], h3[0], h3[1]};
    *(f16x8*)(qp + eo * 8) = ov;
  }
}

// ---------------- proj pass 1: GEMM (no store) -> GN stats only ----------------
// grid (2, 32, 16), block 256.
__global__ __launch_bounds__(256) void proj_stats(
    const _Float16* __restrict__ At, const _Float16* __restrict__ Wpk,
    const float* __restrict__ bias, double* __restrict__ stats) {
  __shared__ _Float16 Bs[128][40];
  const int mt = blockIdx.x;
  const int n0 = blockIdx.y * 128;
  const int b = blockIdx.z;
  const _Float16* Ab = At + (size_t)b * NN * O3;
  const int tid = threadIdx.x, l = tid & 63, wid = tid >> 6;
  const int wm = (wid >> 1) << 6, wn = (wid & 1) << 6;
  const int fr = l & 15, q = l >> 4, kq = q << 3;
  const int am16 = mt * 8 + (wm >> 4);
  const int sr0 = tid >> 2, sc = (tid & 3) << 3;   // rows 0..63, cols {0,8,16,24}

  f32x4 acc[4][4];
#pragma unroll
  for (int i = 0; i < 4; i++)
#pragma unroll
    for (int j = 0; j < 4; j++) acc[i][j] = (f32x4){0.f, 0.f, 0.f, 0.f};

  for (int k0 = 0; k0 < HID; k0 += 32) {
    f16x8 v0 = *(const f16x8*)(Ab + (size_t)(n0 + sr0) * O3 + k0 + sc);
    f16x8 v1 = *(const f16x8*)(Ab + (size_t)(n0 + 64 + sr0) * O3 + k0 + sc);
    f16x8 ah[4];
#pragma unroll
    for (int fm = 0; fm < 4; fm++)
      ah[fm] = *(const f16x8*)(Wpk + ((size_t)((am16 + fm) * 4 + (k0 >> 5)) * 64 + l) * 8);
    __syncthreads();
    *(f16x8*)&Bs[sr0][sc] = v0;
    *(f16x8*)&Bs[64 + sr0][sc] = v1;
    __syncthreads();
    f16x8 bh[4];
#pragma unroll
    for (int fn = 0; fn < 4; fn++)
      bh[fn] = *(const f16x8*)&Bs[wn + fn * 16 + fr][kq];
#pragma unroll
    for (int fm = 0; fm < 4; fm++)
#pragma unroll
      for (int fn = 0; fn < 4; fn++)
        acc[fm][fn] = __builtin_amdgcn_mfma_f32_16x16x32_f16(ah[fm], bh[fn], acc[fm][fn], 0, 0, 0);
  }
  float lsum = 0.f, lsq = 0.f;
#pragma unroll
  for (int fm = 0; fm < 4; fm++) {
    int rowb = mt * 128 + wm + fm * 16 + q * 4;
#pragma unroll
    for (int r = 0; r < 4; r++) {
      float bv = bias[rowb + r];
#pragma unroll
      for (int fn = 0; fn < 4; fn++) {
        float v = acc[fm][fn][r] + bv;
        lsum += v;
        lsq += v * v;
      }
    }
  }
  double ds = (double)lsum, dq = (double)lsq;
#pragma unroll
  for (int off = 32; off; off >>= 1) {
    ds += __shfl_down(ds, off);
    dq += __shfl_down(dq, off);
  }
  __shared__ double sred[8];
  if (l == 0) { sred[wid] = ds; sred[4 + wid] = dq; }
  __syncthreads();
  if (tid == 0) {
    atomicAdd(&stats[b * 2 + 0], sred[0] + sred[1] + sred[2] + sred[3]);
    atomicAdd(&stats[b * 2 + 1], sred[4] + sred[5] + sred[6] + sred[7]);
  }
}

// ---------------- proj pass 2: recompute GEMM, write normalized out ----------------
// grid (2, 32, 16), block 256.
__global__ __launch_bounds__(256) void proj_write(
    const _Float16* __restrict__ At, const _Float16* __restrict__ Wpk,
    const float* __restrict__ bias, float* __restrict__ out,
    const double* __restrict__ stats, const float* __restrict__ gamma,
    const float* __restrict__ beta) {
  __shared__ _Float16 Bs[128][40];
  const int mt = blockIdx.x;
  const int n0 = blockIdx.y * 128;
  const int b = blockIdx.z;
  const _Float16* Ab = At + (size_t)b * NN * O3;
  float* outb = out + (size_t)b * CIN * NN;
  const int tid = threadIdx.x, l = tid & 63, wid = tid >> 6;
  const int wm = (wid >> 1) << 6, wn = (wid & 1) << 6;
  const int fr = l & 15, q = l >> 4, kq = q << 3;
  const int am16 = mt * 8 + (wm >> 4);
  const int sr0 = tid >> 2, sc = (tid & 3) << 3;   // rows 0..63, cols {0,8,16,24}

  const double nels = (double)CIN * (double)NN;
  double S = stats[b * 2 + 0], Q2 = stats[b * 2 + 1];
  double mu = S / nels;
  double var = Q2 / nels - mu * mu;
  const float mean = (float)mu;
  const float rstd = (float)rsqrt(var + 1e-5);

  f32x4 acc[4][4];
#pragma unroll
  for (int i = 0; i < 4; i++)
#pragma unroll
    for (int j = 0; j < 4; j++) acc[i][j] = (f32x4){0.f, 0.f, 0.f, 0.f};

  for (int k0 = 0; k0 < HID; k0 += 32) {
    f16x8 v0 = *(const f16x8*)(Ab + (size_t)(n0 + sr0) * O3 + k0 + sc);
    f16x8 v1 = *(const f16x8*)(Ab + (size_t)(n0 + 64 + sr0) * O3 + k0 + sc);
    f16x8 ah[4];
#pragma unroll
    for (int fm = 0; fm < 4; fm++)
      ah[fm] = *(const f16x8*)(Wpk + ((size_t)((am16 + fm) * 4 + (k0 >> 5)) * 64 + l) * 8);
    __syncthreads();
    *(f16x8*)&Bs[sr0][sc] = v0;
    *(f16x8*)&Bs[64 + sr0][sc] = v1;
    __syncthreads();
    f16x8 bh[4];
#pragma unroll
    for (int fn = 0; fn < 4; fn++)
      bh[fn] = *(const f16x8*)&Bs[wn + fn * 16 + fr][kq];
#pragma unroll
    for (int fm = 0; fm < 4; fm++)
#pragma unroll
      for (int fn = 0; fn < 4; fn++)
        acc[fm][fn] = __builtin_amdgcn_mfma_f32_16x16x32_f16(ah[fm], bh[fn], acc[fm][fn], 0, 0, 0);
  }
#pragma unroll
  for (int fm = 0; fm < 4; fm++) {
    int rowb = mt * 128 + wm + fm * 16 + q * 4;
#pragma unroll
    for (int r = 0; r < 4; r++) {
      int row = rowb + r;
      float bv = bias[row];
      float g = gamma[row] * rstd, bt = beta[row];
      float* dst = outb + (size_t)row * NN + n0 + wn + fr;
#pragma unroll
      for (int fn = 0; fn < 4; fn++) {
        float v = acc[fm][fn][r] + bv;
        dst[fn * 16] = (v - mean) * g + bt;
      }
    }
  }
}

extern "C" void kernel_launch(void* const* d_in, const int* in_sizes, int n_in,
                              void* d_out, int out_size, void* d_ws, size_t ws_size,
                              hipStream_t stream) {
  const float* x     = (const float*)d_in[0];
  const float* Wqkv  = (const float*)d_in[1];
  const float* Wout  = (const float*)d_in[2];
  const float* bout  = (const float*)d_in[3];
  const float* gamma = (const float*)d_in[4];
  const float* beta  = (const float*)d_in[5];
  float* out = (float*)d_out;

  char* ws = (char*)d_ws;
  _Float16* qkvt = (_Float16*)ws;                             // [16][4096][384] f16
  size_t off = (size_t)16 * NN * O3 * 2;                      // 50331648 B
  _Float16* WpkA = (_Float16*)(ws + off); off += 48 * 256 * 8 * 2;   // 196608 B
  _Float16* WpkB = (_Float16*)(ws + off); off += 16 * 256 * 8 * 2;   // 65536 B
  float* ctxg = (float*)(ws + off); off += (size_t)16 * NHEAD * DH * DH * 4;
  float* srow = (float*)(ws + off); off += (size_t)16 * NHEAD * DH * 4;
  double* stats = (double*)(ws + off);

  const int nz = 16 * NHEAD * DH * DH + 16 * NHEAD * DH + 64;
  prep<<<64 + (nz + 255) / 256, 256, 0, stream>>>(Wqkv, Wout, WpkA, WpkB, ctxg, nz);
  gemm_qkv<<<dim3(1536), 256, 0, stream>>>(x, WpkA, qkvt);
  attn1<<<dim3(NHEAD, 16, 8), 256, 0, stream>>>(qkvt, ctxg, srow);
  attn2<<<dim3(16, NHEAD, 16), 256, 0, stream>>>(qkvt, ctxg, srow);
  proj_stats<<<dim3(2, 32, 16), 256, 0, stream>>>(qkvt, WpkB, bout, stats);
  proj_write<<<dim3(2, 32, 16), 256, 0, stream>>>(qkvt, WpkB, bout, out, stats, gamma, beta);
}

// Round 15
// 117.620 us; speedup vs baseline: 1.2172x; 1.0209x over previous
//
#include <hip/hip_runtime.h>

#define NN 4096
#define CIN 256
#define O3 384
#define HID 128
#define NHEAD 4
#define DH 32

typedef float f32x4 __attribute__((ext_vector_type(4)));
typedef _Float16 f16x8 __attribute__((ext_vector_type(8)));
typedef _Float16 f16x4 __attribute__((ext_vector_type(4)));
typedef _Float16 f16x2 __attribute__((ext_vector_type(2)));
typedef __fp16 fp16x2_raw __attribute__((ext_vector_type(2)));

__device__ __forceinline__ f16x2 pkrtz(float a, float b) {
  fp16x2_raw r = __builtin_amdgcn_cvt_pkrtz(a, b);
  return __builtin_bit_cast(f16x2, r);
}

// ---------------- prepass: pack W into MFMA A-frag layout (f16), zero scratch ----------------
// Wpk layout: [(m16*K32 + k32)*64 + l] -> f16x8 : row = m16*16 + (l&15), k = k32*32 + (l>>4)*8 + j
__global__ __launch_bounds__(256) void prep(
    const float* __restrict__ Wqkv, const float* __restrict__ Wout,
    _Float16* __restrict__ WpkA, _Float16* __restrict__ WpkB,
    float* __restrict__ zbase, int nz) {
  const int bid = blockIdx.x, tid = threadIdx.x;
  if (bid < 48) {                       // Wqkv: 24 m16 * 8 k32 * 64 = 12288 threads
    int t = bid * 256 + tid;
    int l = t & 63, mk = t >> 6;
    int k32 = mk & 7, m16 = mk >> 3;
    int row = m16 * 16 + (l & 15), k = k32 * 32 + (l >> 4) * 8;
    const float* s = Wqkv + (size_t)row * CIN + k;
    f16x8 o;
#pragma unroll
    for (int j = 0; j < 8; j++) o[j] = (_Float16)s[j];
    *(f16x8*)(WpkA + (size_t)t * 8) = o;
  } else if (bid < 64) {                // Wout: 16 m16 * 4 k32 * 64 = 4096 threads
    int t = (bid - 48) * 256 + tid;
    int l = t & 63, mk = t >> 6;
    int k32 = mk & 3, m16 = mk >> 2;
    int row = m16 * 16 + (l & 15), k = k32 * 32 + (l >> 4) * 8;
    const float* s = Wout + (size_t)row * HID + k;
    f16x8 o;
#pragma unroll
    for (int j = 0; j < 8; j++) o[j] = (_Float16)s[j];
    *(f16x8*)(WpkB + (size_t)t * 8) = o;
  } else {
    int i = (bid - 64) * 256 + tid;
    if (i < nz) zbase[i] = 0.f;
  }
}

// ---------------- GEMM1: qkvt[b][n][o] = (Wqkv @ X[b])^T, f16 out ----------------
// v16 = v10 + __launch_bounds__(256, 3): occupancy was register-limited to 2 waves/SIMD
// (arch 84 VGPR + 64 AGPR acc + xr/ah live ranges ~= 180-200 total -> 512/180 = 2 -> the
// constant 24% OccupancyPercent across all variants). Forcing 3 blocks/CU caps total regs
// at ~170, buying +50% resident waves to cover the barrier-drain stalls.
__global__ __launch_bounds__(256, 3) void gemm_qkv(
    const float* __restrict__ X, const _Float16* __restrict__ Wpk,
    _Float16* __restrict__ Yt) {
  __shared__ _Float16 Bs[2][128 * 40];  // 20480 B; epilogue reuses as [64][132] f16 (16896 B)
  const int orig = blockIdx.x;          // 1536 blocks, 1536 % 8 == 0
  const int swz = (orig & 7) * 192 + (orig >> 3);
  const int mt = swz % 3;
  const int nb = swz / 3;
  const int n0 = (nb & 31) << 7;
  const int b  = nb >> 5;
  const float* Xb = X + (size_t)b * CIN * NN;
  _Float16* Yb = Yt + (size_t)b * NN * O3;
  const int tid = threadIdx.x, l = tid & 63, wid = tid >> 6;
  const int wm = (wid >> 1) << 6, wn = (wid & 1) << 6;
  const int fr = l & 15, q = l >> 4;
  const int b_n = (tid & 31) << 2, b_kk = (tid >> 5) << 2;
  const int am16 = mt * 8 + (wm >> 4);
  // write-side swizzle: rows r = b_n+j share r>>2 = tid&31 (j<4)
  const int tp = tid & 31;
  const int swz3 = ((tp ^ (tp >> 2)) & 3) << 1;           // even, 3-bit
  const int gw4 = (((tid >> 5) ^ swz3) << 2);             // f16 offset of swizzled 8B granule
  // read-side swizzle: per-fn offsets, loop-invariant
  int roff[4];
#pragma unroll
  for (int fn = 0; fn < 4; fn++) {
    const int R = wn + fn * 16 + fr;
    const int sR = ((R >> 2) ^ (R >> 4)) & 3;
    roff[fn] = R * 40 + ((q ^ sR) << 3);                  // f16 units, 16B aligned
  }

#define LOADX(dst, t_) do { \
    _Pragma("unroll") \
    for (int r_ = 0; r_ < 4; r_++) \
      dst[r_] = *(const f32x4*)(Xb + (size_t)((t_) * 32 + b_kk + r_) * NN + n0 + b_n); \
  } while (0)
#define LOADAH(dst, t_) do { \
    _Pragma("unroll") \
    for (int fm_ = 0; fm_ < 4; fm_++) \
      dst[fm_] = *(const f16x8*)(Wpk + ((size_t)((am16 + fm_) * 8 + (t_)) * 64 + l) * 8); \
  } while (0)
#define CVTW(buf_, src) do { \
    _Pragma("unroll") \
    for (int j_ = 0; j_ < 4; j_++) { \
      f16x2 p0_ = pkrtz(src[0][j_], src[1][j_]); \
      f16x2 p1_ = pkrtz(src[2][j_], src[3][j_]); \
      *(f16x4*)&Bs[buf_][(b_n + j_) * 40 + gw4] = (f16x4){p0_[0], p0_[1], p1_[0], p1_[1]}; \
    } } while (0)

  f32x4 xr[3][4];                     // 3-deep rotation: X chunk in flight 2 k-steps
  f16x8 ah[2][4];
  f32x4 acc[4][4];
#pragma unroll
  for (int i = 0; i < 4; i++)
#pragma unroll
    for (int j = 0; j < 4; j++) acc[i][j] = (f32x4){0.f, 0.f, 0.f, 0.f};

  // prologue: chunk0 -> Bs[0]; issue ah(0), chunk1, chunk2 (stay in flight across barrier)
  LOADX(xr[0], 0);
  CVTW(0, xr[0]);
  LOADAH(ah[0], 0);
  LOADX(xr[1], 1);
  LOADX(xr[2], 2);
  asm volatile("s_waitcnt lgkmcnt(0)" ::: "memory");
  __builtin_amdgcn_s_barrier();
  __builtin_amdgcn_sched_barrier(0);

#pragma unroll
  for (int t = 0; t < 8; t++) {
    const int cur = t & 1, nxt = cur ^ 1;
    f16x8 bh[4];
#pragma unroll
    for (int fn = 0; fn < 4; fn++)
      bh[fn] = *(const f16x8*)&Bs[cur][roff[fn]];
#pragma unroll
    for (int fm = 0; fm < 4; fm++)
#pragma unroll
      for (int fn = 0; fn < 4; fn++)
        acc[fm][fn] = __builtin_amdgcn_mfma_f32_16x16x32_f16(ah[cur][fm], bh[fn], acc[fm][fn], 0, 0, 0);
    if (t < 7) {
      CVTW(nxt, xr[(t + 1) % 3]);   // chunk t+1, issued 2+ k-steps ago
      LOADAH(ah[nxt], t + 1);       // issue next Wpk frags (L2, 1-step flight)
      if (t < 5) LOADX(xr[(t + 3) % 3], t + 3);  // FIFO: ah-wait forces only this iter's X
    }
    asm volatile("s_waitcnt lgkmcnt(0)" ::: "memory");
    __builtin_amdgcn_s_barrier();
    __builtin_amdgcn_sched_barrier(0);
  }

  // ---- LDS-transpose epilogue: 2 passes of 64 n-rows, coalesced f16x8 stores ----
  _Float16* Ep = &Bs[0][0];           // [64][132] f16, 16896 B, aliases staging buffer
  const int st_n = tid >> 4;          // 0..15
  const int st_m8 = (tid & 15) * 8;   // 0..120
#pragma unroll
  for (int p = 0; p < 2; p++) {
    if ((wid & 1) == p) {             // waves with wn == p*64 hold rows n_local = fn*16+fr
#pragma unroll
      for (int fm = 0; fm < 4; fm++) {
        const int ml = wm + fm * 16 + q * 4;
#pragma unroll
        for (int fn = 0; fn < 4; fn++) {
          const int nl = fn * 16 + fr;
          f16x2 h0 = pkrtz(acc[fm][fn][0], acc[fm][fn][1]);
          f16x2 h1 = pkrtz(acc[fm][fn][2], acc[fm][fn][3]);
          *(f16x4*)&Ep[nl * 132 + ml] = (f16x4){h0[0], h0[1], h1[0], h1[1]};
        }
      }
    }
    __syncthreads();
#pragma unroll
    for (int s = 0; s < 4; s++) {
      const int nl = s * 16 + st_n;
      f16x4 lo = *(const f16x4*)&Ep[nl * 132 + st_m8];
      f16x4 hi = *(const f16x4*)&Ep[nl * 132 + st_m8 + 4];
      f16x8 v = (f16x8){lo[0], lo[1], lo[2], lo[3], hi[0], hi[1], hi[2], hi[3]};
      *(f16x8*)(Yb + (size_t)(n0 + p * 64 + nl) * O3 + mt * 128 + st_m8) = v;
    }
    if (p == 0) __syncthreads();      // protect buffer reuse for pass 1
  }
#undef LOADX
#undef LOADAH
#undef CVTW
}

// ---------------- attn1: exp(K)·V^T outer product + row sums ----------------
// grid (NHEAD, 16, 8), block 256 (4 waves); qkvt layout [n][384]
__global__ __launch_bounds__(256) void attn1(
    const _Float16* __restrict__ qkvt, float* __restrict__ ctx_raw,
    float* __restrict__ srow_raw) {
  const int h = blockIdx.x, b = blockIdx.y, ns = blockIdx.z;
  const _Float16* base = qkvt + (size_t)b * NN * O3;
  const _Float16* Kb = base + HID + h * DH;
  const _Float16* Vb = base + 2 * HID + h * DH;
  float* ctx = ctx_raw + (size_t)(b * NHEAD + h) * (DH * DH);
  float* srow = srow_raw + (size_t)(b * NHEAD + h) * DH;
  __shared__ __align__(16) float Es[64][36];
  __shared__ __align__(16) float Vs[64][36];
  __shared__ float ctxs[DH][DH + 1];
  __shared__ float srow_s[DH];
  const int tid = threadIdx.x, l = tid & 63, w = tid >> 6;
  const int d4 = (l >> 3) << 2, e4 = (l & 7) << 2;
  if (tid < DH) srow_s[tid] = 0.f;
  for (int i = tid; i < DH * (DH + 1); i += 256) (&ctxs[0][0])[i] = 0.f;
  float sacc[4] = {0.f, 0.f, 0.f, 0.f};
  float acc[4][4];
#pragma unroll
  for (int i = 0; i < 4; i++)
#pragma unroll
    for (int j = 0; j < 4; j++) acc[i][j] = 0.f;

  for (int c = 0; c < 8; c++) {
    const int n0 = ns * 512 + c * 64;
    const size_t roff = (size_t)(n0 + l) * O3 + w * 8;
    f16x8 kv = *(const f16x8*)(Kb + roff);
    f16x8 vv = *(const f16x8*)(Vb + roff);
    __syncthreads();
    float4 e0, e1, v0, v1;
    e0.x = __expf((float)kv[0]); e0.y = __expf((float)kv[1]);
    e0.z = __expf((float)kv[2]); e0.w = __expf((float)kv[3]);
    e1.x = __expf((float)kv[4]); e1.y = __expf((float)kv[5]);
    e1.z = __expf((float)kv[6]); e1.w = __expf((float)kv[7]);
    v0.x = (float)vv[0]; v0.y = (float)vv[1]; v0.z = (float)vv[2]; v0.w = (float)vv[3];
    v1.x = (float)vv[4]; v1.y = (float)vv[5]; v1.z = (float)vv[6]; v1.w = (float)vv[7];
    *(float4*)&Es[l][w * 8] = e0;
    *(float4*)&Es[l][w * 8 + 4] = e1;
    *(float4*)&Vs[l][w * 8] = v0;
    *(float4*)&Vs[l][w * 8 + 4] = v1;
    __syncthreads();
#pragma unroll
    for (int it = 0; it < 16; it++) {
      const int n = w + 4 * it;
      float ka[4], va[4];
      *(float4*)ka = *(const float4*)&Es[n][d4];
      *(float4*)va = *(const float4*)&Vs[n][e4];
#pragma unroll
      for (int i = 0; i < 4; i++) {
        sacc[i] += ka[i];
#pragma unroll
        for (int j = 0; j < 4; j++) acc[i][j] = fmaf(ka[i], va[j], acc[i][j]);
      }
    }
  }
  // srow: sacc identical across the 8 lanes sharing d4 within a wave -> one contributes
  if ((l & 7) == 0) {
#pragma unroll
    for (int i = 0; i < 4; i++) atomicAdd(&srow_s[d4 + i], sacc[i]);
  }
#pragma unroll
  for (int i = 0; i < 4; i++)
#pragma unroll
    for (int j = 0; j < 4; j++) atomicAdd(&ctxs[d4 + i][e4 + j], acc[i][j]);
  __syncthreads();
  for (int i = tid; i < DH * DH; i += 256) atomicAdd(&ctx[i], ctxs[i >> 5][i & 31]);
  if (tid < DH) atomicAdd(&srow[tid], srow_s[tid]);
}

// ---------------- attn2: thread-per-column q-softmax + out = ctx^T q, in-place f16 ----------------
// grid (16, NHEAD, 16), block 256
__global__ __launch_bounds__(256) void attn2(
    _Float16* __restrict__ qkvt, const float* __restrict__ ctx_raw,
    const float* __restrict__ srow_raw) {
  const int ns = blockIdx.x, h = blockIdx.y, b = blockIdx.z;
  const float* cg = ctx_raw + (size_t)(b * NHEAD + h) * (DH * DH);
  const float* sr = srow_raw + (size_t)(b * NHEAD + h) * DH;
  __shared__ float ctxs[DH][DH + 1];
  const int tid = threadIdx.x;
  for (int i = tid; i < DH * DH; i += 256) ctxs[i >> 5][i & 31] = cg[i] / sr[i >> 5];
  __syncthreads();
  const int n = ns * 256 + tid;
  _Float16* qp = qkvt + ((size_t)b * NN + n) * O3 + h * DH;
  float qv[DH];
#pragma unroll
  for (int i = 0; i < 4; i++) {
    f16x8 v = *(const f16x8*)(qp + i * 8);
#pragma unroll
    for (int j = 0; j < 8; j++) qv[i * 8 + j] = (float)v[j];
  }
  float m = -1e30f;
#pragma unroll
  for (int d = 0; d < DH; d++) m = fmaxf(m, qv[d]);
  float s = 0.f;
#pragma unroll
  for (int d = 0; d < DH; d++) { qv[d] = __expf(qv[d] - m); s += qv[d]; }
  float inv = 0.17677669529663687f / s;  // scale = 32^-0.5
#pragma unroll
  for (int d = 0; d < DH; d++) qv[d] *= inv;
#pragma unroll
  for (int eo = 0; eo < 4; eo++) {
    float o[8];
#pragma unroll
    for (int j = 0; j < 8; j++) o[j] = 0.f;
#pragma unroll
    for (int d = 0; d < DH; d++) {
      float qd = qv[d];
#pragma unroll
      for (int j = 0; j < 8; j++) o[j] = fmaf(ctxs[d][eo * 8 + j], qd, o[j]);
    }
    f16x2 h0 = pkrtz(o[0], o[1]);
    f16x2 h1 = pkrtz(o[2], o[3]);
    f16x2 h2 = pkrtz(o[4], o[5]);
    f16x2 h3 = pkrtz(o[6], o[7]);
    f16x8 ov = (f16x8){h0[0], h0[1], h1[0], h1[1], h2[0], h2[1], h3[0], h3[1]};
    *(f16x8*)(qp + eo * 8) = ov;
  }
}

// ---------------- proj pass 1: GEMM (no store) -> GN stats only ----------------
// grid (2, 32, 16), block 256.
__global__ __launch_bounds__(256) void proj_stats(
    const _Float16* __restrict__ At, const _Float16* __restrict__ Wpk,
    const float* __restrict__ bias, double* __restrict__ stats) {
  __shared__ _Float16 Bs[128][40];
  const int mt = blockIdx.x;
  const int n0 = blockIdx.y * 128;
  const int b = blockIdx.z;
  const _Float16* Ab = At + (size_t)b * NN * O3;
  const int tid = threadIdx.x, l = tid & 63, wid = tid >> 6;
  const int wm = (wid >> 1) << 6, wn = (wid & 1) << 6;
  const int fr = l & 15, q = l >> 4, kq = q << 3;
  const int am16 = mt * 8 + (wm >> 4);
  const int sr0 = tid >> 2, sc = (tid & 3) << 3;   // rows 0..63, cols {0,8,16,24}

  f32x4 acc[4][4];
#pragma unroll
  for (int i = 0; i < 4; i++)
#pragma unroll
    for (int j = 0; j < 4; j++) acc[i][j] = (f32x4){0.f, 0.f, 0.f, 0.f};

  for (int k0 = 0; k0 < HID; k0 += 32) {
    f16x8 v0 = *(const f16x8*)(Ab + (size_t)(n0 + sr0) * O3 + k0 + sc);
    f16x8 v1 = *(const f16x8*)(Ab + (size_t)(n0 + 64 + sr0) * O3 + k0 + sc);
    f16x8 ah[4];
#pragma unroll
    for (int fm = 0; fm < 4; fm++)
      ah[fm] = *(const f16x8*)(Wpk + ((size_t)((am16 + fm) * 4 + (k0 >> 5)) * 64 + l) * 8);
    __syncthreads();
    *(f16x8*)&Bs[sr0][sc] = v0;
    *(f16x8*)&Bs[64 + sr0][sc] = v1;
    __syncthreads();
    f16x8 bh[4];
#pragma unroll
    for (int fn = 0; fn < 4; fn++)
      bh[fn] = *(const f16x8*)&Bs[wn + fn * 16 + fr][kq];
#pragma unroll
    for (int fm = 0; fm < 4; fm++)
#pragma unroll
      for (int fn = 0; fn < 4; fn++)
        acc[fm][fn] = __builtin_amdgcn_mfma_f32_16x16x32_f16(ah[fm], bh[fn], acc[fm][fn], 0, 0, 0);
  }
  float lsum = 0.f, lsq = 0.f;
#pragma unroll
  for (int fm = 0; fm < 4; fm++) {
    int rowb = mt * 128 + wm + fm * 16 + q * 4;
#pragma unroll
    for (int r = 0; r < 4; r++) {
      float bv = bias[rowb + r];
#pragma unroll
      for (int fn = 0; fn < 4; fn++) {
        float v = acc[fm][fn][r] + bv;
        lsum += v;
        lsq += v * v;
      }
    }
  }
  double ds = (double)lsum, dq = (double)lsq;
#pragma unroll
  for (int off = 32; off; off >>= 1) {
    ds += __shfl_down(ds, off);
    dq += __shfl_down(dq, off);
  }
  __shared__ double sred[8];
  if (l == 0) { sred[wid] = ds; sred[4 + wid] = dq; }
  __syncthreads();
  if (tid == 0) {
    atomicAdd(&stats[b * 2 + 0], sred[0] + sred[1] + sred[2] + sred[3]);
    atomicAdd(&stats[b * 2 + 1], sred[4] + sred[5] + sred[6] + sred[7]);
  }
}

// ---------------- proj pass 2: recompute GEMM, write normalized out ----------------
// grid (2, 32, 16), block 256.
__global__ __launch_bounds__(256) void proj_write(
    const _Float16* __restrict__ At, const _Float16* __restrict__ Wpk,
    const float* __restrict__ bias, float* __restrict__ out,
    const double* __restrict__ stats, const float* __restrict__ gamma,
    const float* __restrict__ beta) {
  __shared__ _Float16 Bs[128][40];
  const int mt = blockIdx.x;
  const int n0 = blockIdx.y * 128;
  const int b = blockIdx.z;
  const _Float16* Ab = At + (size_t)b * NN * O3;
  float* outb = out + (size_t)b * CIN * NN;
  const int tid = threadIdx.x, l = tid & 63, wid = tid >> 6;
  const int wm = (wid >> 1) << 6, wn = (wid & 1) << 6;
  const int fr = l & 15, q = l >> 4, kq = q << 3;
  const int am16 = mt * 8 + (wm >> 4);
  const int sr0 = tid >> 2, sc = (tid & 3) << 3;   // rows 0..63, cols {0,8,16,24}

  const double nels = (double)CIN * (double)NN;
  double S = stats[b * 2 + 0], Q2 = stats[b * 2 + 1];
  double mu = S / nels;
  double var = Q2 / nels - mu * mu;
  const float mean = (float)mu;
  const float rstd = (float)rsqrt(var + 1e-5);

  f32x4 acc[4][4];
#pragma unroll
  for (int i = 0; i < 4; i++)
#pragma unroll
    for (int j = 0; j < 4; j++) acc[i][j] = (f32x4){0.f, 0.f, 0.f, 0.f};

  for (int k0 = 0; k0 < HID; k0 += 32) {
    f16x8 v0 = *(const f16x8*)(Ab + (size_t)(n0 + sr0) * O3 + k0 + sc);
    f16x8 v1 = *(const f16x8*)(Ab + (size_t)(n0 + 64 + sr0) * O3 + k0 + sc);
    f16x8 ah[4];
#pragma unroll
    for (int fm = 0; fm < 4; fm++)
      ah[fm] = *(const f16x8*)(Wpk + ((size_t)((am16 + fm) * 4 + (k0 >> 5)) * 64 + l) * 8);
    __syncthreads();
    *(f16x8*)&Bs[sr0][sc] = v0;
    *(f16x8*)&Bs[64 + sr0][sc] = v1;
    __syncthreads();
    f16x8 bh[4];
#pragma unroll
    for (int fn = 0; fn < 4; fn++)
      bh[fn] = *(const f16x8*)&Bs[wn + fn * 16 + fr][kq];
#pragma unroll
    for (int fm = 0; fm < 4; fm++)
#pragma unroll
      for (int fn = 0; fn < 4; fn++)
        acc[fm][fn] = __builtin_amdgcn_mfma_f32_16x16x32_f16(ah[fm], bh[fn], acc[fm][fn], 0, 0, 0);
  }
#pragma unroll
  for (int fm = 0; fm < 4; fm++) {
    int rowb = mt * 128 + wm + fm * 16 + q * 4;
#pragma unroll
    for (int r = 0; r < 4; r++) {
      int row = rowb + r;
      float bv = bias[row];
      float g = gamma[row] * rstd, bt = beta[row];
      float* dst = outb + (size_t)row * NN + n0 + wn + fr;
#pragma unroll
      for (int fn = 0; fn < 4; fn++) {
        float v = acc[fm][fn][r] + bv;
        dst[fn * 16] = (v - mean) * g + bt;
      }
    }
  }
}

extern "C" void kernel_launch(void* const* d_in, const int* in_sizes, int n_in,
                              void* d_out, int out_size, void* d_ws, size_t ws_size,
                              hipStream_t stream) {
  const float* x     = (const float*)d_in[0];
  const float* Wqkv  = (const float*)d_in[1];
  const float* Wout  = (const float*)d_in[2];
  const float* bout  = (const float*)d_in[3];
  const float* gamma = (const float*)d_in[4];
  const float* beta  = (const float*)d_in[5];
  float* out = (float*)d_out;

  char* ws = (char*)d_ws;
  _Float16* qkvt = (_Float16*)ws;                             // [16][4096][384] f16
  size_t off = (size_t)16 * NN * O3 * 2;                      // 50331648 B
  _Float16* WpkA = (_Float16*)(ws + off); off += 48 * 256 * 8 * 2;   // 196608 B
  _Float16* WpkB = (_Float16*)(ws + off); off += 16 * 256 * 8 * 2;   // 65536 B
  float* ctxg = (float*)(ws + off); off += (size_t)16 * NHEAD * DH * DH * 4;
  float* srow = (float*)(ws + off); off += (size_t)16 * NHEAD * DH * 4;
  double* stats = (double*)(ws + off);

  const int nz = 16 * NHEAD * DH * DH + 16 * NHEAD * DH + 64;
  prep<<<64 + (nz + 255) / 256, 256, 0, stream>>>(Wqkv, Wout, WpkA, WpkB, ctxg, nz);
  gemm_qkv<<<dim3(1536), 256, 0, stream>>>(x, WpkA, qkvt);
  attn1<<<dim3(NHEAD, 16, 8), 256, 0, stream>>>(qkvt, ctxg, srow);
  attn2<<<dim3(16, NHEAD, 16), 256, 0, stream>>>(qkvt, ctxg, srow);
  proj_stats<<<dim3(2, 32, 16), 256, 0, stream>>>(qkvt, WpkB, bout, stats);
  proj_write<<<dim3(2, 32, 16), 256, 0, stream>>>(qkvt, WpkB, bout, out, stats, gamma, beta);
}